// Round 1
// baseline (1102.388 us; speedup 1.0000x reference)
//
#include <hip/hip_runtime.h>
#include <cstdint>
#include <cstddef>

#define CDIV(a,b) (((a)+(b)-1)/(b))

constexpr int N_ = 100000;
constexpr int E_ = 600000;
constexpr int D_ = 128;
constexpr int G_ = 2048;
constexpr int NHID_ = 512;
constexpr int NOUT_ = 768;
constexpr float EPS_ = 1e-5f;

__device__ __forceinline__ float wave_sum(float v){
#pragma unroll
  for (int m = 32; m; m >>= 1) v += __shfl_xor(v, m, 64);
  return v;
}
__device__ __forceinline__ float wave_max(float v){
#pragma unroll
  for (int m = 32; m; m >>= 1) v = fmaxf(v, __shfl_xor(v, m, 64));
  return v;
}
__device__ __forceinline__ float lrelu02(float v){ return v > 0.f ? v : 0.2f * v; }

// ---------------- CSR build ----------------
__global__ void k_count(const int* __restrict__ dst, int* __restrict__ cnt){
  int e = blockIdx.x * 256 + threadIdx.x;
  if (e < E_) atomicAdd(&cnt[dst[e]], 1);
}

__global__ void k_dinv(const int* __restrict__ cnt, float* __restrict__ dinv){
  int i = blockIdx.x * 256 + threadIdx.x;
  if (i < N_) dinv[i] = rsqrtf((float)(cnt[i] + 1));  // +1 self-loop
}

__global__ void k_scan1(const int* __restrict__ cnt, int* __restrict__ ro, int* __restrict__ bs){
  __shared__ int s[256];
  int tid = threadIdx.x;
  int i = blockIdx.x * 256 + tid;
  int v = (i < N_) ? cnt[i] : 0;
  s[tid] = v; __syncthreads();
  for (int off = 1; off < 256; off <<= 1){
    int add = (tid >= off) ? s[tid - off] : 0;
    __syncthreads();
    s[tid] += add;
    __syncthreads();
  }
  if (i < N_) ro[i] = s[tid] - v;             // exclusive within block
  if (tid == 255) bs[blockIdx.x] = s[255];    // block total
}

__global__ void k_scan2(int* __restrict__ bs, int nb){
  if (threadIdx.x == 0 && blockIdx.x == 0){
    int run = 0;
    for (int b = 0; b < nb; ++b){ int t = bs[b]; bs[b] = run; run += t; }
  }
}

__global__ void k_scan3(int* __restrict__ ro, const int* __restrict__ bs){
  int i = blockIdx.x * 256 + threadIdx.x;
  if (i < N_) ro[i] += bs[i >> 8];
  if (i == N_) ro[N_] = E_;
}

__global__ void k_fill(const int* __restrict__ src, const int* __restrict__ dst,
                       const int* __restrict__ ro, int* __restrict__ cur, int* __restrict__ csr){
  int e = blockIdx.x * 256 + threadIdx.x;
  if (e < E_){
    int d = dst[e];
    int p = atomicAdd(&cur[d], 1);
    csr[ro[d] + p] = src[e];
  }
}

__global__ void k_bounds(const int* __restrict__ batch, int* __restrict__ gs){
  int g = blockIdx.x * 256 + threadIdx.x;
  if (g > G_) return;
  int lo = 0, hi = N_;
  while (lo < hi){ int mid = (lo + hi) >> 1; if (batch[mid] < g) lo = mid + 1; else hi = mid; }
  gs[g] = lo;
}

// ---------------- node matmul: Y[N,128] = X[N,128] @ W[128,128] ----------------
__global__ __launch_bounds__(256) void k_matmul128(const float* __restrict__ X,
                                                   const float* __restrict__ W,
                                                   float* __restrict__ Y){
  __shared__ float xs[32][33];
  __shared__ float ws[32][128];
  int tid = threadIdx.x;
  int rg = tid >> 5, cg = tid & 31;
  int row0 = blockIdx.x * 32;
  float acc[4][4] = {};
  for (int kc = 0; kc < 128; kc += 32){
    {
      int r = tid >> 3, kq = tid & 7;
      float4 v = *(const float4*)&X[(size_t)(row0 + r) * 128 + kc + kq * 4];
      xs[r][kq*4+0] = v.x; xs[r][kq*4+1] = v.y; xs[r][kq*4+2] = v.z; xs[r][kq*4+3] = v.w;
    }
    {
      int cq = tid & 31, krb = tid >> 5;
#pragma unroll
      for (int p = 0; p < 4; ++p){
        int kr = p * 8 + krb;
        float4 v = *(const float4*)&W[(size_t)(kc + kr) * 128 + cq * 4];
        *(float4*)&ws[kr][cq * 4] = v;
      }
    }
    __syncthreads();
#pragma unroll
    for (int k = 0; k < 32; ++k){
      float a0 = xs[rg*4+0][k], a1 = xs[rg*4+1][k], a2 = xs[rg*4+2][k], a3 = xs[rg*4+3][k];
      float b0 = ws[k][cg], b1 = ws[k][cg+32], b2 = ws[k][cg+64], b3 = ws[k][cg+96];
      acc[0][0] += a0*b0; acc[0][1] += a0*b1; acc[0][2] += a0*b2; acc[0][3] += a0*b3;
      acc[1][0] += a1*b0; acc[1][1] += a1*b1; acc[1][2] += a1*b2; acc[1][3] += a1*b3;
      acc[2][0] += a2*b0; acc[2][1] += a2*b1; acc[2][2] += a2*b2; acc[2][3] += a2*b3;
      acc[3][0] += a3*b0; acc[3][1] += a3*b1; acc[3][2] += a3*b2; acc[3][3] += a3*b3;
    }
    __syncthreads();
  }
#pragma unroll
  for (int i = 0; i < 4; ++i)
#pragma unroll
    for (int j = 0; j < 4; ++j)
      Y[(size_t)(row0 + rg*4 + i) * 128 + cg + 32*j] = acc[i][j];
}

// ---------------- GCN aggregate: out[i] = b + dinv_i*(sum_e dinv_s*h_s + dinv_i*h_i) ----------------
__global__ void k_gcn_agg(const float* __restrict__ h, const int* __restrict__ ro,
                          const int* __restrict__ csr, const float* __restrict__ dinv,
                          const float* __restrict__ bias, float* __restrict__ outb){
  int node = blockIdx.x * 4 + (threadIdx.x >> 6);
  int lane = threadIdx.x & 63;
  if (node >= N_) return;
  float di = dinv[node];
  const float2* h2 = (const float2*)h;
  float2 acc = make_float2(0.f, 0.f);
  int s0 = ro[node], s1 = ro[node + 1];
  for (int e = s0; e < s1; ++e){
    int s = csr[e];
    float w = dinv[s];
    float2 v = h2[(size_t)s * 64 + lane];
    acc.x += w * v.x; acc.y += w * v.y;
  }
  float2 hi = h2[(size_t)node * 64 + lane];
  float2 bb = ((const float2*)bias)[lane];
  float2 o;
  o.x = di * (acc.x + di * hi.x) + bb.x;
  o.y = di * (acc.y + di * hi.y) + bb.y;
  ((float2*)outb)[(size_t)node * 64 + lane] = o;
}

// ---------------- BN over nodes ----------------
__global__ void k_bn_stats(const float* __restrict__ x, float* __restrict__ sums){
  __shared__ float sa[256], sb[256];
  int f = threadIdx.x & 127, half = threadIdx.x >> 7;
  float a = 0.f, b = 0.f;
  for (int r = blockIdx.x * 2 + half; r < N_; r += gridDim.x * 2){
    float v = x[(size_t)r * 128 + f];
    a += v; b += v * v;
  }
  sa[threadIdx.x] = a; sb[threadIdx.x] = b;
  __syncthreads();
  if (threadIdx.x < 128){
    a = sa[threadIdx.x] + sa[threadIdx.x + 128];
    b = sb[threadIdx.x] + sb[threadIdx.x + 128];
    atomicAdd(&sums[f], a);
    atomicAdd(&sums[128 + f], b);
  }
}

__global__ void k_bn_finalize(const float* __restrict__ sums, const float* __restrict__ g,
                              const float* __restrict__ be, float* __restrict__ ss){
  int f = threadIdx.x;
  if (f >= 128) return;
  float mean = sums[f] / (float)N_;
  float var = sums[128 + f] / (float)N_ - mean * mean;
  var = fmaxf(var, 0.f);
  float sc = g[f] * rsqrtf(var + EPS_);
  ss[f] = sc;
  ss[128 + f] = be[f] - mean * sc;
}

// t = relu(t*scale+shift) [+ res], in place, float4 over N*128
__global__ void k_bn_apply(float* __restrict__ t, const float* __restrict__ ss,
                           const float* __restrict__ res){
  int i = blockIdx.x * 256 + threadIdx.x;
  const int total4 = N_ * 32;
  if (i >= total4) return;
  float4 v = ((const float4*)t)[i];
  int f4 = i & 31;
  float4 sc = ((const float4*)ss)[f4];
  float4 sh = ((const float4*)ss)[32 + f4];
  float4 r;
  r.x = fmaxf(v.x * sc.x + sh.x, 0.f);
  r.y = fmaxf(v.y * sc.y + sh.y, 0.f);
  r.z = fmaxf(v.z * sc.z + sh.z, 0.f);
  r.w = fmaxf(v.w * sc.w + sh.w, 0.f);
  if (res){
    float4 rv = ((const float4*)res)[i];
    r.x += rv.x; r.y += rv.y; r.z += rv.z; r.w += rv.w;
  }
  ((float4*)t)[i] = r;
}

// ---------------- GAT ----------------
__global__ void k_dot(const float* __restrict__ h, const float* __restrict__ asrc,
                      const float* __restrict__ adst, float* __restrict__ al, float* __restrict__ ar){
  int node = blockIdx.x * 4 + (threadIdx.x >> 6);
  int lane = threadIdx.x & 63;
  if (node >= N_) return;
  float2 hv = ((const float2*)h)[(size_t)node * 64 + lane];
  float2 s = ((const float2*)asrc)[lane];
  float2 d = ((const float2*)adst)[lane];
  float ps = hv.x * s.x + hv.y * s.y;
  float pd = hv.x * d.x + hv.y * d.y;
  ps = wave_sum(ps); pd = wave_sum(pd);
  if (lane == 0){ al[node] = ps; ar[node] = pd; }
}

__global__ void k_gat_agg(const float* __restrict__ h, const int* __restrict__ ro,
                          const int* __restrict__ csr, const float* __restrict__ al,
                          const float* __restrict__ ar, const float* __restrict__ bias,
                          float* __restrict__ outb){
  int node = blockIdx.x * 4 + (threadIdx.x >> 6);
  int lane = threadIdx.x & 63;
  if (node >= N_) return;
  float ali = al[node], ari = ar[node];
  int s0 = ro[node], s1 = ro[node + 1];
  float selfl = lrelu02(ali + ari);
  float m = selfl;
  for (int e = s0 + lane; e < s1; e += 64)
    m = fmaxf(m, lrelu02(al[csr[e]] + ari));
  m = wave_max(m);
  float lsum = (lane == 0) ? expf(selfl - m) : 0.f;
  for (int e = s0 + lane; e < s1; e += 64)
    lsum += expf(lrelu02(al[csr[e]] + ari) - m);
  lsum = wave_sum(lsum);
  float invd = 1.f / lsum;
  const float2* h2 = (const float2*)h;
  float wse = expf(selfl - m) * invd;
  float2 hv = h2[(size_t)node * 64 + lane];
  float2 acc = make_float2(wse * hv.x, wse * hv.y);
  for (int e = s0; e < s1; ++e){
    int s = csr[e];
    float w = expf(lrelu02(al[s] + ari) - m) * invd;
    float2 sv = h2[(size_t)s * 64 + lane];
    acc.x += w * sv.x; acc.y += w * sv.y;
  }
  float2 bb = ((const float2*)bias)[lane];
  ((float2*)outb)[(size_t)node * 64 + lane] = make_float2(acc.x + bb.x, acc.y + bb.y);
}

// ---------------- pool ----------------
__global__ void k_pool(const float* __restrict__ xn, const int* __restrict__ gs,
                       float* __restrict__ pooled){
  int g = blockIdx.x, f = threadIdx.x;
  int s = gs[g], e = gs[g + 1];
  float a = 0.f;
  for (int n = s; n < e; ++n) a += xn[(size_t)n * 128 + f];
  pooled[(size_t)g * 128 + f] = a;
}

// ---------------- generic MLP GEMM: C[M,Nc] = A[M,K]@W[K,Nc] + b (opt relu) ----------------
__global__ __launch_bounds__(256) void k_gemm(const float* __restrict__ A, const float* __restrict__ W,
                                              const float* __restrict__ bias, float* __restrict__ C,
                                              int M, int K, int Nc, int relu){
  __shared__ float As[64][17];
  __shared__ float Ws[16][64];
  int tid = threadIdx.x;
  int ty = tid >> 4, tx = tid & 15;
  int rb = blockIdx.y * 64, cb = blockIdx.x * 64;
  float acc[4][4] = {};
  for (int k0 = 0; k0 < K; k0 += 16){
    {
      int r = tid >> 2, kq = tid & 3;
      float4 v = *(const float4*)&A[(size_t)(rb + r) * K + k0 + kq * 4];
      As[r][kq*4+0] = v.x; As[r][kq*4+1] = v.y; As[r][kq*4+2] = v.z; As[r][kq*4+3] = v.w;
    }
    {
      int kk = tid >> 4, cq = tid & 15;
      float4 v = *(const float4*)&W[(size_t)(k0 + kk) * Nc + cb + cq * 4];
      *(float4*)&Ws[kk][cq * 4] = v;
    }
    __syncthreads();
#pragma unroll
    for (int k = 0; k < 16; ++k){
      float a0 = As[ty*4+0][k], a1 = As[ty*4+1][k], a2 = As[ty*4+2][k], a3 = As[ty*4+3][k];
      float b0 = Ws[k][tx], b1 = Ws[k][tx+16], b2 = Ws[k][tx+32], b3 = Ws[k][tx+48];
      acc[0][0] += a0*b0; acc[0][1] += a0*b1; acc[0][2] += a0*b2; acc[0][3] += a0*b3;
      acc[1][0] += a1*b0; acc[1][1] += a1*b1; acc[1][2] += a1*b2; acc[1][3] += a1*b3;
      acc[2][0] += a2*b0; acc[2][1] += a2*b1; acc[2][2] += a2*b2; acc[2][3] += a2*b3;
      acc[3][0] += a3*b0; acc[3][1] += a3*b1; acc[3][2] += a3*b2; acc[3][3] += a3*b3;
    }
    __syncthreads();
  }
#pragma unroll
  for (int i = 0; i < 4; ++i)
#pragma unroll
    for (int j = 0; j < 4; ++j){
      int c = cb + tx + 16 * j;
      float v = acc[i][j] + bias[c];
      if (relu) v = fmaxf(v, 0.f);
      C[(size_t)(rb + ty*4 + i) * Nc + c] = v;
    }
}

// ---------------- final layernorm over 768 ----------------
__global__ void k_layernorm(const float* __restrict__ xin, const float* __restrict__ g,
                            const float* __restrict__ b, float* __restrict__ out){
  __shared__ float red[8];
  int row = blockIdx.x, tid = threadIdx.x;
  float v0 = xin[(size_t)row*768 + tid];
  float v1 = xin[(size_t)row*768 + tid + 256];
  float v2 = xin[(size_t)row*768 + tid + 512];
  float s = v0 + v1 + v2;
  float q = v0*v0 + v1*v1 + v2*v2;
  s = wave_sum(s); q = wave_sum(q);
  int wid = tid >> 6;
  if ((tid & 63) == 0){ red[wid] = s; red[4 + wid] = q; }
  __syncthreads();
  if (tid == 0){
    float ts = red[0] + red[1] + red[2] + red[3];
    float tq = red[4] + red[5] + red[6] + red[7];
    float mean = ts / 768.f;
    float var = tq / 768.f - mean * mean;
    red[0] = mean; red[1] = rsqrtf(fmaxf(var, 0.f) + EPS_);
  }
  __syncthreads();
  float mean = red[0], inv = red[1];
  out[(size_t)row*768 + tid]       = (v0 - mean) * inv * g[tid]       + b[tid];
  out[(size_t)row*768 + tid + 256] = (v1 - mean) * inv * g[tid + 256] + b[tid + 256];
  out[(size_t)row*768 + tid + 512] = (v2 - mean) * inv * g[tid + 512] + b[tid + 512];
}

extern "C" void kernel_launch(void* const* d_in, const int* in_sizes, int n_in,
                              void* d_out, int out_size, void* d_ws, size_t ws_size,
                              hipStream_t stream){
  const float* x     = (const float*)d_in[0];
  const int*   ei    = (const int*)d_in[1];
  const int*   src   = ei;
  const int*   dst   = ei + E_;
  const int*   batch = (const int*)d_in[2];
  const float* W1 = (const float*)d_in[3];  const float* b1 = (const float*)d_in[4];
  const float* W2 = (const float*)d_in[5];  const float* b2 = (const float*)d_in[6];
  const float* W3 = (const float*)d_in[7];  const float* b3 = (const float*)d_in[8];
  const float* Wa = (const float*)d_in[9];  const float* ba = (const float*)d_in[10];
  const float* a_src = (const float*)d_in[11]; const float* a_dst = (const float*)d_in[12];
  const float* g1 = (const float*)d_in[13]; const float* be1 = (const float*)d_in[14];
  const float* g2 = (const float*)d_in[15]; const float* be2 = (const float*)d_in[16];
  const float* g3 = (const float*)d_in[17]; const float* be3 = (const float*)d_in[18];
  const float* ga = (const float*)d_in[19]; const float* bea = (const float*)d_in[20];
  const float* Wl1 = (const float*)d_in[21]; const float* bl1 = (const float*)d_in[22];
  const float* Wl2 = (const float*)d_in[23]; const float* bl2 = (const float*)d_in[24];
  const float* Wl3 = (const float*)d_in[25]; const float* bl3 = (const float*)d_in[26];
  const float* Wl4 = (const float*)d_in[27]; const float* bl4 = (const float*)d_in[28];
  const float* gln = (const float*)d_in[29]; const float* bln = (const float*)d_in[30];
  float* out = (float*)d_out;

  char* base = (char*)d_ws;
  size_t off = 0;
  auto alloc = [&](size_t bytes)->char*{
    char* p = base + off;
    off += (bytes + 255) & ~(size_t)255;
    return p;
  };
  int*   cnt    = (int*)  alloc((size_t)N_ * 4);
  float* dinv   = (float*)alloc((size_t)N_ * 4);
  int*   ro     = (int*)  alloc((size_t)(N_ + 1) * 4);
  int*   bs     = (int*)  alloc(512 * 4);
  int*   cur    = (int*)  alloc((size_t)N_ * 4);
  int*   csr    = (int*)  alloc((size_t)E_ * 4);
  int*   gstart = (int*)  alloc((size_t)(G_ + 1) * 4);
  float* al     = (float*)alloc((size_t)N_ * 4);
  float* ar     = (float*)alloc((size_t)N_ * 4);
  float* bnsum  = (float*)alloc(256 * 4);
  float* bnss   = (float*)alloc(256 * 4);
  float* bufA   = (float*)alloc((size_t)N_ * D_ * 4);
  float* bufB   = (float*)alloc((size_t)N_ * D_ * 4);
  float* bufC   = (float*)alloc((size_t)N_ * D_ * 4);
  float* pooled = (float*)alloc((size_t)G_ * D_ * 4);
  float* m1     = (float*)alloc((size_t)G_ * NHID_ * 4);
  float* m2     = (float*)alloc((size_t)G_ * NHID_ * 4);
  float* m4     = (float*)alloc((size_t)G_ * NOUT_ * 4);
  (void)ws_size; (void)in_sizes; (void)n_in; (void)out_size;

  const int nbE = CDIV(E_, 256), nbN = CDIV(N_, 256);

  hipMemsetAsync(cnt, 0, (size_t)N_ * 4, stream);
  k_count<<<nbE, 256, 0, stream>>>(dst, cnt);
  k_dinv<<<nbN, 256, 0, stream>>>(cnt, dinv);
  k_scan1<<<nbN, 256, 0, stream>>>(cnt, ro, bs);
  k_scan2<<<1, 64, 0, stream>>>(bs, nbN);
  k_scan3<<<CDIV(N_ + 1, 256), 256, 0, stream>>>(ro, bs);
  hipMemsetAsync(cur, 0, (size_t)N_ * 4, stream);
  k_fill<<<nbE, 256, 0, stream>>>(src, dst, ro, cur, csr);
  k_bounds<<<CDIV(G_ + 1, 256), 256, 0, stream>>>(batch, gstart);

  auto bn_block = [&](float* t, const float* res, const float* g, const float* be){
    hipMemsetAsync(bnsum, 0, 256 * 4, stream);
    k_bn_stats<<<1024, 256, 0, stream>>>(t, bnsum);
    k_bn_finalize<<<1, 128, 0, stream>>>(bnsum, g, be, bnss);
    k_bn_apply<<<CDIV(N_ * 32, 256), 256, 0, stream>>>(t, bnss, res);
  };

  // GCN layer 1: x -> bufC
  k_matmul128<<<N_ / 32, 256, 0, stream>>>(x, W1, bufB);
  k_gcn_agg<<<N_ / 4, 256, 0, stream>>>(bufB, ro, csr, dinv, b1, bufC);
  bn_block(bufC, x, g1, be1);
  // GCN layer 2: bufC -> bufA
  k_matmul128<<<N_ / 32, 256, 0, stream>>>(bufC, W2, bufB);
  k_gcn_agg<<<N_ / 4, 256, 0, stream>>>(bufB, ro, csr, dinv, b2, bufA);
  bn_block(bufA, bufC, g2, be2);
  // GCN layer 3: bufA -> bufC
  k_matmul128<<<N_ / 32, 256, 0, stream>>>(bufA, W3, bufB);
  k_gcn_agg<<<N_ / 4, 256, 0, stream>>>(bufB, ro, csr, dinv, b3, bufC);
  bn_block(bufC, bufA, g3, be3);
  // GAT: bufC -> bufA
  k_matmul128<<<N_ / 32, 256, 0, stream>>>(bufC, Wa, bufB);
  k_dot<<<N_ / 4, 256, 0, stream>>>(bufB, a_src, a_dst, al, ar);
  k_gat_agg<<<N_ / 4, 256, 0, stream>>>(bufB, ro, csr, al, ar, ba, bufA);
  bn_block(bufA, nullptr, ga, bea);
  // pool
  k_pool<<<G_, 128, 0, stream>>>(bufA, gstart, pooled);
  // MLP
  k_gemm<<<dim3(NHID_ / 64, G_ / 64), 256, 0, stream>>>(pooled, Wl1, bl1, m1, G_, D_, NHID_, 1);
  k_gemm<<<dim3(NHID_ / 64, G_ / 64), 256, 0, stream>>>(m1, Wl2, bl2, m2, G_, NHID_, NHID_, 1);
  k_gemm<<<dim3(NHID_ / 64, G_ / 64), 256, 0, stream>>>(m2, Wl3, bl3, m1, G_, NHID_, NHID_, 1);
  k_gemm<<<dim3(NOUT_ / 64, G_ / 64), 256, 0, stream>>>(m1, Wl4, bl4, m4, G_, NHID_, NOUT_, 0);
  k_layernorm<<<G_, 256, 0, stream>>>(m4, gln, bln, out);
}

// Round 2
// 889.433 us; speedup vs baseline: 1.2394x; 1.2394x over previous
//
#include <hip/hip_runtime.h>
#include <cstdint>
#include <cstddef>

#define CDIV(a,b) (((a)+(b)-1)/(b))

constexpr int N_ = 100000;
constexpr int E_ = 600000;
constexpr int D_ = 128;
constexpr int G_ = 2048;
constexpr int NHID_ = 512;
constexpr int NOUT_ = 768;
constexpr float EPS_ = 1e-5f;
constexpr int AGG_BLOCKS = 2048;   // 4 waves each -> 8192 waves grid-striding nodes

__device__ __forceinline__ float wave_sum(float v){
#pragma unroll
  for (int m = 32; m; m >>= 1) v += __shfl_xor(v, m, 64);
  return v;
}
__device__ __forceinline__ float lrelu02(float v){ return v > 0.f ? v : 0.2f * v; }

// ---------------- CSR build ----------------
__global__ void k_count(const int* __restrict__ dst, int* __restrict__ cnt){
  int e = blockIdx.x * 256 + threadIdx.x;
  if (e < E_) atomicAdd(&cnt[dst[e]], 1);
}

__global__ void k_dinv(const int* __restrict__ cnt, float* __restrict__ dinv){
  int i = blockIdx.x * 256 + threadIdx.x;
  if (i < N_) dinv[i] = rsqrtf((float)(cnt[i] + 1));  // +1 self-loop
}

__global__ void k_scan1(const int* __restrict__ cnt, int* __restrict__ ro, int* __restrict__ bs){
  __shared__ int s[256];
  int tid = threadIdx.x;
  int i = blockIdx.x * 256 + tid;
  int v = (i < N_) ? cnt[i] : 0;
  s[tid] = v; __syncthreads();
  for (int off = 1; off < 256; off <<= 1){
    int add = (tid >= off) ? s[tid - off] : 0;
    __syncthreads();
    s[tid] += add;
    __syncthreads();
  }
  if (i < N_) ro[i] = s[tid] - v;
  if (tid == 255) bs[blockIdx.x] = s[255];
}

__global__ void k_scan2(int* __restrict__ bs, int nb){
  if (threadIdx.x == 0 && blockIdx.x == 0){
    int run = 0;
    for (int b = 0; b < nb; ++b){ int t = bs[b]; bs[b] = run; run += t; }
  }
}

__global__ void k_scan3(int* __restrict__ ro, const int* __restrict__ bs){
  int i = blockIdx.x * 256 + threadIdx.x;
  if (i < N_) ro[i] += bs[i >> 8];
  if (i == N_) ro[N_] = E_;
}

__global__ void k_fill(const int* __restrict__ src, const int* __restrict__ dst,
                       const int* __restrict__ ro, int* __restrict__ cur, int* __restrict__ csr){
  int e = blockIdx.x * 256 + threadIdx.x;
  if (e < E_){
    int d = dst[e];
    int p = atomicAdd(&cur[d], 1);
    csr[ro[d] + p] = src[e];
  }
}

__global__ void k_bounds(const int* __restrict__ batch, int* __restrict__ gs){
  int g = blockIdx.x * 256 + threadIdx.x;
  if (g > G_) return;
  int lo = 0, hi = N_;
  while (lo < hi){ int mid = (lo + hi) >> 1; if (batch[mid] < g) lo = mid + 1; else hi = mid; }
  gs[g] = lo;
}

// ---------------- fused node matmul ----------------
// Y[N,128] = T(X)[N,128] @ W[128,128]
// T(v) = ss ? relu(v*sc+sh) (+ res) : v ; optionally materialize T(X) to xnew
// optionally epilogue: al = Y.a_src, ar = Y.a_dst  (per row)
__global__ __launch_bounds__(256) void k_matmul128f(const float* __restrict__ X,
                                                    const float* __restrict__ W,
                                                    float* __restrict__ Y,
                                                    const float* __restrict__ ss,
                                                    const float* __restrict__ res,
                                                    float* __restrict__ xnew,
                                                    const float* __restrict__ asrc,
                                                    const float* __restrict__ adst,
                                                    float* __restrict__ al,
                                                    float* __restrict__ ar){
  __shared__ float xs[32][33];
  __shared__ float ws[32][128];
  int tid = threadIdx.x;
  int rg = tid >> 5, cg = tid & 31;
  int row0 = blockIdx.x * 32;
  float acc[4][4] = {};
  for (int kc = 0; kc < 128; kc += 32){
    {
      int r = tid >> 3, kq = tid & 7;
      int f0 = kc + kq * 4;
      size_t xoff = (size_t)(row0 + r) * 128 + f0;
      float4 v = *(const float4*)&X[xoff];
      if (ss){
        float4 sc = *(const float4*)&ss[f0];
        float4 sh = *(const float4*)&ss[128 + f0];
        v.x = fmaxf(v.x * sc.x + sh.x, 0.f);
        v.y = fmaxf(v.y * sc.y + sh.y, 0.f);
        v.z = fmaxf(v.z * sc.z + sh.z, 0.f);
        v.w = fmaxf(v.w * sc.w + sh.w, 0.f);
        if (res){
          float4 rv = *(const float4*)&res[xoff];
          v.x += rv.x; v.y += rv.y; v.z += rv.z; v.w += rv.w;
        }
        if (xnew) *(float4*)&xnew[xoff] = v;
      }
      xs[r][kq*4+0] = v.x; xs[r][kq*4+1] = v.y; xs[r][kq*4+2] = v.z; xs[r][kq*4+3] = v.w;
    }
    {
      int cq = tid & 31, krb = tid >> 5;
#pragma unroll
      for (int p = 0; p < 4; ++p){
        int kr = p * 8 + krb;
        float4 v = *(const float4*)&W[(size_t)(kc + kr) * 128 + cq * 4];
        *(float4*)&ws[kr][cq * 4] = v;
      }
    }
    __syncthreads();
#pragma unroll
    for (int k = 0; k < 32; ++k){
      float a0 = xs[rg*4+0][k], a1 = xs[rg*4+1][k], a2 = xs[rg*4+2][k], a3 = xs[rg*4+3][k];
      float b0 = ws[k][cg], b1 = ws[k][cg+32], b2 = ws[k][cg+64], b3 = ws[k][cg+96];
      acc[0][0] += a0*b0; acc[0][1] += a0*b1; acc[0][2] += a0*b2; acc[0][3] += a0*b3;
      acc[1][0] += a1*b0; acc[1][1] += a1*b1; acc[1][2] += a1*b2; acc[1][3] += a1*b3;
      acc[2][0] += a2*b0; acc[2][1] += a2*b1; acc[2][2] += a2*b2; acc[2][3] += a2*b3;
      acc[3][0] += a3*b0; acc[3][1] += a3*b1; acc[3][2] += a3*b2; acc[3][3] += a3*b3;
    }
    __syncthreads();
  }
#pragma unroll
  for (int i = 0; i < 4; ++i)
#pragma unroll
    for (int j = 0; j < 4; ++j)
      Y[(size_t)(row0 + rg*4 + i) * 128 + cg + 32*j] = acc[i][j];

  if (al){
    float pal[4] = {0,0,0,0}, par[4] = {0,0,0,0};
#pragma unroll
    for (int j = 0; j < 4; ++j){
      float as_ = asrc[cg + 32*j], ad_ = adst[cg + 32*j];
#pragma unroll
      for (int i = 0; i < 4; ++i){ pal[i] += acc[i][j]*as_; par[i] += acc[i][j]*ad_; }
    }
#pragma unroll
    for (int m = 16; m; m >>= 1){
#pragma unroll
      for (int i = 0; i < 4; ++i){
        pal[i] += __shfl_xor(pal[i], m, 64);
        par[i] += __shfl_xor(par[i], m, 64);
      }
    }
    if (cg == 0){
#pragma unroll
      for (int i = 0; i < 4; ++i){
        al[row0 + rg*4 + i] = pal[i];
        ar[row0 + rg*4 + i] = par[i];
      }
    }
  }
}

// ---------------- GCN aggregate (fused bias + BN stats partials) ----------------
__global__ __launch_bounds__(256) void k_gcn_agg2(const float* __restrict__ h, const int* __restrict__ ro,
                          const int* __restrict__ csr, const float* __restrict__ dinv,
                          const float* __restrict__ bias, float* __restrict__ outb,
                          float4* __restrict__ pbuf){
  int wid = threadIdx.x >> 6, lane = threadIdx.x & 63;
  const float2* h2 = (const float2*)h;
  float2 bb = ((const float2*)bias)[lane];
  float2 S = make_float2(0.f, 0.f), Q = make_float2(0.f, 0.f);
  for (int node = blockIdx.x * 4 + wid; node < N_; node += AGG_BLOCKS * 4){
    int s0 = ro[node], s1 = ro[node + 1];
    int deg = s1 - s0;
    float di = dinv[node];
    float2 hi = h2[(size_t)node * 64 + lane];
    float2 acc = make_float2(0.f, 0.f);
    if (deg <= 64){
      int sidx = 0; float wl = 0.f;
      if (lane < deg){ sidx = csr[s0 + lane]; wl = dinv[sidx]; }
      int j = 0;
      for (; j + 4 <= deg; j += 4){
        int sa = __shfl(sidx, j, 64),   sb = __shfl(sidx, j+1, 64);
        int sc = __shfl(sidx, j+2, 64), sd = __shfl(sidx, j+3, 64);
        float wa = __shfl(wl, j, 64),   wb = __shfl(wl, j+1, 64);
        float wc = __shfl(wl, j+2, 64), wd = __shfl(wl, j+3, 64);
        float2 va = h2[(size_t)sa*64+lane], vb = h2[(size_t)sb*64+lane];
        float2 vc = h2[(size_t)sc*64+lane], vd = h2[(size_t)sd*64+lane];
        acc.x += wa*va.x + wb*vb.x + wc*vc.x + wd*vd.x;
        acc.y += wa*va.y + wb*vb.y + wc*vc.y + wd*vd.y;
      }
      for (; j < deg; ++j){
        int s = __shfl(sidx, j, 64); float w = __shfl(wl, j, 64);
        float2 v = h2[(size_t)s*64+lane];
        acc.x += w*v.x; acc.y += w*v.y;
      }
    } else {
      for (int base = s0; base < s1; base += 64){
        int c = min(64, s1 - base);
        int sidx = 0; float wl = 0.f;
        if (lane < c){ sidx = csr[base + lane]; wl = dinv[sidx]; }
        for (int j = 0; j < c; ++j){
          int s = __shfl(sidx, j, 64); float w = __shfl(wl, j, 64);
          float2 v = h2[(size_t)s*64+lane];
          acc.x += w*v.x; acc.y += w*v.y;
        }
      }
    }
    float2 o;
    o.x = di * (acc.x + di * hi.x) + bb.x;
    o.y = di * (acc.y + di * hi.y) + bb.y;
    ((float2*)outb)[(size_t)node * 64 + lane] = o;
    S.x += o.x; S.y += o.y; Q.x += o.x*o.x; Q.y += o.y*o.y;
  }
  __shared__ float4 sred[4][64];
  sred[wid][lane] = make_float4(S.x, S.y, Q.x, Q.y);
  __syncthreads();
  if (wid == 0){
    float4 t = sred[0][lane];
    float4 u1 = sred[1][lane], u2 = sred[2][lane], u3 = sred[3][lane];
    t.x += u1.x + u2.x + u3.x;
    t.y += u1.y + u2.y + u3.y;
    t.z += u1.z + u2.z + u3.z;
    t.w += u1.w + u2.w + u3.w;
    pbuf[(size_t)blockIdx.x * 64 + lane] = t;
  }
}

// ---------------- GAT aggregate (no-max softmax, fused bias + stats) ----------------
__global__ __launch_bounds__(256) void k_gat_agg2(const float* __restrict__ h, const int* __restrict__ ro,
                          const int* __restrict__ csr, const float* __restrict__ al,
                          const float* __restrict__ ar, const float* __restrict__ bias,
                          float* __restrict__ outb, float4* __restrict__ pbuf){
  int wid = threadIdx.x >> 6, lane = threadIdx.x & 63;
  const float2* h2 = (const float2*)h;
  float2 bb = ((const float2*)bias)[lane];
  float2 S = make_float2(0.f, 0.f), Q = make_float2(0.f, 0.f);
  for (int node = blockIdx.x * 4 + wid; node < N_; node += AGG_BLOCKS * 4){
    int s0 = ro[node], s1 = ro[node + 1];
    int deg = s1 - s0;
    float ari = ar[node], ali = al[node];
    float pself = __expf(lrelu02(ali + ari));
    float2 hi = h2[(size_t)node * 64 + lane];
    float2 acc;
    if (deg <= 64){
      int sidx = 0; float p = 0.f;
      if (lane < deg){ sidx = csr[s0 + lane]; p = __expf(lrelu02(al[sidx] + ari)); }
      float invd = 1.f / (wave_sum(p) + pself);
      float wl = p * invd;
      float wsf = pself * invd;
      acc = make_float2(wsf * hi.x, wsf * hi.y);
      int j = 0;
      for (; j + 4 <= deg; j += 4){
        int sa = __shfl(sidx, j, 64),   sb = __shfl(sidx, j+1, 64);
        int sc = __shfl(sidx, j+2, 64), sd = __shfl(sidx, j+3, 64);
        float wa = __shfl(wl, j, 64),   wb = __shfl(wl, j+1, 64);
        float wc = __shfl(wl, j+2, 64), wd = __shfl(wl, j+3, 64);
        float2 va = h2[(size_t)sa*64+lane], vb = h2[(size_t)sb*64+lane];
        float2 vc = h2[(size_t)sc*64+lane], vd = h2[(size_t)sd*64+lane];
        acc.x += wa*va.x + wb*vb.x + wc*vc.x + wd*vd.x;
        acc.y += wa*va.y + wb*vb.y + wc*vc.y + wd*vd.y;
      }
      for (; j < deg; ++j){
        int s = __shfl(sidx, j, 64); float w = __shfl(wl, j, 64);
        float2 v = h2[(size_t)s*64+lane];
        acc.x += w*v.x; acc.y += w*v.y;
      }
    } else {
      float denom = pself;
      for (int base = s0; base < s1; base += 64){
        int c = min(64, s1 - base);
        float p = 0.f;
        if (lane < c) p = __expf(lrelu02(al[csr[base + lane]] + ari));
        denom += wave_sum(p);
      }
      float invd = 1.f / denom;
      float wsf = pself * invd;
      acc = make_float2(wsf * hi.x, wsf * hi.y);
      for (int base = s0; base < s1; base += 64){
        int c = min(64, s1 - base);
        int sidx = 0; float wl = 0.f;
        if (lane < c){ sidx = csr[base + lane]; wl = __expf(lrelu02(al[sidx] + ari)) * invd; }
        for (int j = 0; j < c; ++j){
          int s = __shfl(sidx, j, 64); float w = __shfl(wl, j, 64);
          float2 v = h2[(size_t)s*64+lane];
          acc.x += w*v.x; acc.y += w*v.y;
        }
      }
    }
    float2 o = make_float2(acc.x + bb.x, acc.y + bb.y);
    ((float2*)outb)[(size_t)node * 64 + lane] = o;
    S.x += o.x; S.y += o.y; Q.x += o.x*o.x; Q.y += o.y*o.y;
  }
  __shared__ float4 sred[4][64];
  sred[wid][lane] = make_float4(S.x, S.y, Q.x, Q.y);
  __syncthreads();
  if (wid == 0){
    float4 t = sred[0][lane];
    float4 u1 = sred[1][lane], u2 = sred[2][lane], u3 = sred[3][lane];
    t.x += u1.x + u2.x + u3.x;
    t.y += u1.y + u2.y + u3.y;
    t.z += u1.z + u2.z + u3.z;
    t.w += u1.w + u2.w + u3.w;
    pbuf[(size_t)blockIdx.x * 64 + lane] = t;
  }
}

// ---------------- BN partial reduce -> scale/shift ----------------
__global__ void k_bn_reduce(const float4* __restrict__ pbuf, const float* __restrict__ g,
                            const float* __restrict__ be, float* __restrict__ ss){
  int c = blockIdx.x;  // feature pair 2c, 2c+1
  float4 a = make_float4(0.f, 0.f, 0.f, 0.f);
  for (int r = threadIdx.x; r < AGG_BLOCKS; r += 256){
    float4 v = pbuf[(size_t)r * 64 + c];
    a.x += v.x; a.y += v.y; a.z += v.z; a.w += v.w;
  }
  __shared__ float4 s[256];
  s[threadIdx.x] = a; __syncthreads();
  for (int off = 128; off; off >>= 1){
    if (threadIdx.x < off){
      float4 o = s[threadIdx.x + off];
      s[threadIdx.x].x += o.x; s[threadIdx.x].y += o.y;
      s[threadIdx.x].z += o.z; s[threadIdx.x].w += o.w;
    }
    __syncthreads();
  }
  if (threadIdx.x == 0){
    float4 t = s[0];
    float inv_n = 1.f / (float)N_;
    float mean0 = t.x * inv_n, mean1 = t.y * inv_n;
    float var0 = fmaxf(t.z * inv_n - mean0 * mean0, 0.f);
    float var1 = fmaxf(t.w * inv_n - mean1 * mean1, 0.f);
    float sc0 = g[2*c]   * rsqrtf(var0 + EPS_);
    float sc1 = g[2*c+1] * rsqrtf(var1 + EPS_);
    ss[2*c] = sc0; ss[2*c+1] = sc1;
    ss[128 + 2*c] = be[2*c] - mean0 * sc0;
    ss[128 + 2*c+1] = be[2*c+1] - mean1 * sc1;
  }
}

// ---------------- pool with fused BN-apply+relu ----------------
__global__ void k_pool2(const float* __restrict__ xn, const int* __restrict__ gs,
                        const float* __restrict__ ss, float* __restrict__ pooled){
  int g = blockIdx.x, f = threadIdx.x & 127, half = threadIdx.x >> 7;
  int s = gs[g], e = gs[g + 1];
  float sc = ss[f], sh = ss[128 + f];
  float a = 0.f;
  for (int n = s + half; n < e; n += 2)
    a += fmaxf(xn[(size_t)n * 128 + f] * sc + sh, 0.f);
  __shared__ float red[256];
  red[threadIdx.x] = a; __syncthreads();
  if (half == 0) pooled[(size_t)g * 128 + f] = red[f] + red[128 + f];
}

// ---------------- generic MLP GEMM ----------------
__global__ __launch_bounds__(256) void k_gemm(const float* __restrict__ A, const float* __restrict__ W,
                                              const float* __restrict__ bias, float* __restrict__ C,
                                              int M, int K, int Nc, int relu){
  __shared__ float As[64][17];
  __shared__ float Ws[16][64];
  int tid = threadIdx.x;
  int ty = tid >> 4, tx = tid & 15;
  int rb = blockIdx.y * 64, cb = blockIdx.x * 64;
  float acc[4][4] = {};
  for (int k0 = 0; k0 < K; k0 += 16){
    {
      int r = tid >> 2, kq = tid & 3;
      float4 v = *(const float4*)&A[(size_t)(rb + r) * K + k0 + kq * 4];
      As[r][kq*4+0] = v.x; As[r][kq*4+1] = v.y; As[r][kq*4+2] = v.z; As[r][kq*4+3] = v.w;
    }
    {
      int kk = tid >> 4, cq = tid & 15;
      float4 v = *(const float4*)&W[(size_t)(k0 + kk) * Nc + cb + cq * 4];
      *(float4*)&Ws[kk][cq * 4] = v;
    }
    __syncthreads();
#pragma unroll
    for (int k = 0; k < 16; ++k){
      float a0 = As[ty*4+0][k], a1 = As[ty*4+1][k], a2 = As[ty*4+2][k], a3 = As[ty*4+3][k];
      float b0 = Ws[k][tx], b1 = Ws[k][tx+16], b2 = Ws[k][tx+32], b3 = Ws[k][tx+48];
      acc[0][0] += a0*b0; acc[0][1] += a0*b1; acc[0][2] += a0*b2; acc[0][3] += a0*b3;
      acc[1][0] += a1*b0; acc[1][1] += a1*b1; acc[1][2] += a1*b2; acc[1][3] += a1*b3;
      acc[2][0] += a2*b0; acc[2][1] += a2*b1; acc[2][2] += a2*b2; acc[2][3] += a2*b3;
      acc[3][0] += a3*b0; acc[3][1] += a3*b1; acc[3][2] += a3*b2; acc[3][3] += a3*b3;
    }
    __syncthreads();
  }
#pragma unroll
  for (int i = 0; i < 4; ++i)
#pragma unroll
    for (int j = 0; j < 4; ++j){
      int c = cb + tx + 16 * j;
      float v = acc[i][j] + bias[c];
      if (relu) v = fmaxf(v, 0.f);
      C[(size_t)(rb + ty*4 + i) * Nc + c] = v;
    }
}

// ---------------- final layernorm over 768 ----------------
__global__ void k_layernorm(const float* __restrict__ xin, const float* __restrict__ g,
                            const float* __restrict__ b, float* __restrict__ out){
  __shared__ float red[8];
  int row = blockIdx.x, tid = threadIdx.x;
  float v0 = xin[(size_t)row*768 + tid];
  float v1 = xin[(size_t)row*768 + tid + 256];
  float v2 = xin[(size_t)row*768 + tid + 512];
  float s = v0 + v1 + v2;
  float q = v0*v0 + v1*v1 + v2*v2;
  s = wave_sum(s); q = wave_sum(q);
  int wid = tid >> 6;
  if ((tid & 63) == 0){ red[wid] = s; red[4 + wid] = q; }
  __syncthreads();
  if (tid == 0){
    float ts = red[0] + red[1] + red[2] + red[3];
    float tq = red[4] + red[5] + red[6] + red[7];
    float mean = ts / 768.f;
    float var = tq / 768.f - mean * mean;
    red[0] = mean; red[1] = rsqrtf(fmaxf(var, 0.f) + EPS_);
  }
  __syncthreads();
  float mean = red[0], inv = red[1];
  out[(size_t)row*768 + tid]       = (v0 - mean) * inv * g[tid]       + b[tid];
  out[(size_t)row*768 + tid + 256] = (v1 - mean) * inv * g[tid + 256] + b[tid + 256];
  out[(size_t)row*768 + tid + 512] = (v2 - mean) * inv * g[tid + 512] + b[tid + 512];
}

extern "C" void kernel_launch(void* const* d_in, const int* in_sizes, int n_in,
                              void* d_out, int out_size, void* d_ws, size_t ws_size,
                              hipStream_t stream){
  const float* x     = (const float*)d_in[0];
  const int*   ei    = (const int*)d_in[1];
  const int*   src   = ei;
  const int*   dst   = ei + E_;
  const int*   batch = (const int*)d_in[2];
  const float* W1 = (const float*)d_in[3];  const float* b1 = (const float*)d_in[4];
  const float* W2 = (const float*)d_in[5];  const float* b2 = (const float*)d_in[6];
  const float* W3 = (const float*)d_in[7];  const float* b3 = (const float*)d_in[8];
  const float* Wa = (const float*)d_in[9];  const float* ba = (const float*)d_in[10];
  const float* a_src = (const float*)d_in[11]; const float* a_dst = (const float*)d_in[12];
  const float* g1 = (const float*)d_in[13]; const float* be1 = (const float*)d_in[14];
  const float* g2 = (const float*)d_in[15]; const float* be2 = (const float*)d_in[16];
  const float* g3 = (const float*)d_in[17]; const float* be3 = (const float*)d_in[18];
  const float* ga = (const float*)d_in[19]; const float* bea = (const float*)d_in[20];
  const float* Wl1 = (const float*)d_in[21]; const float* bl1 = (const float*)d_in[22];
  const float* Wl2 = (const float*)d_in[23]; const float* bl2 = (const float*)d_in[24];
  const float* Wl3 = (const float*)d_in[25]; const float* bl3 = (const float*)d_in[26];
  const float* Wl4 = (const float*)d_in[27]; const float* bl4 = (const float*)d_in[28];
  const float* gln = (const float*)d_in[29]; const float* bln = (const float*)d_in[30];
  float* out = (float*)d_out;

  char* base = (char*)d_ws;
  size_t off = 0;
  auto alloc = [&](size_t bytes)->char*{
    char* p = base + off;
    off += (bytes + 255) & ~(size_t)255;
    return p;
  };
  int*   cnt    = (int*)  alloc((size_t)N_ * 4);
  float* dinv   = (float*)alloc((size_t)N_ * 4);
  int*   ro     = (int*)  alloc((size_t)(N_ + 1) * 4);
  int*   bs     = (int*)  alloc(512 * 4);
  int*   cur    = (int*)  alloc((size_t)N_ * 4);
  int*   csr    = (int*)  alloc((size_t)E_ * 4);
  int*   gstart = (int*)  alloc((size_t)(G_ + 1) * 4);
  float* al     = (float*)alloc((size_t)N_ * 4);
  float* ar     = (float*)alloc((size_t)N_ * 4);
  float* ss     = (float*)alloc(256 * 4);
  float4* pbuf  = (float4*)alloc((size_t)AGG_BLOCKS * 64 * 16);
  float* bufH   = (float*)alloc((size_t)N_ * D_ * 4);
  float* bufY   = (float*)alloc((size_t)N_ * D_ * 4);
  float* xres   = (float*)alloc((size_t)N_ * D_ * 4);
  float* pooled = (float*)alloc((size_t)G_ * D_ * 4);
  float* m1     = (float*)alloc((size_t)G_ * NHID_ * 4);
  float* m2     = (float*)alloc((size_t)G_ * NHID_ * 4);
  float* m4     = (float*)alloc((size_t)G_ * NOUT_ * 4);
  (void)ws_size; (void)in_sizes; (void)n_in; (void)out_size;

  const int nbE = CDIV(E_, 256), nbN = CDIV(N_, 256);

  hipMemsetAsync(cnt, 0, (size_t)N_ * 4, stream);
  k_count<<<nbE, 256, 0, stream>>>(dst, cnt);
  k_dinv<<<nbN, 256, 0, stream>>>(cnt, dinv);
  k_scan1<<<nbN, 256, 0, stream>>>(cnt, ro, bs);
  k_scan2<<<1, 64, 0, stream>>>(bs, nbN);
  k_scan3<<<CDIV(N_ + 1, 256), 256, 0, stream>>>(ro, bs);
  hipMemsetAsync(cur, 0, (size_t)N_ * 4, stream);
  k_fill<<<nbE, 256, 0, stream>>>(src, dst, ro, cur, csr);
  k_bounds<<<CDIV(G_ + 1, 256), 256, 0, stream>>>(batch, gstart);

  // L1: h = x @ W1 ; y1 = agg + b1 (+stats) ; ss1
  k_matmul128f<<<N_/32, 256, 0, stream>>>(x, W1, bufH, nullptr, nullptr, nullptr,
                                          nullptr, nullptr, nullptr, nullptr);
  k_gcn_agg2<<<AGG_BLOCKS, 256, 0, stream>>>(bufH, ro, csr, dinv, b1, bufY, pbuf);
  k_bn_reduce<<<64, 256, 0, stream>>>(pbuf, g1, be1, ss);
  // L2: x1 = relu(bn(y1)) + x ; h = x1 @ W2 ; y2 ; ss2
  k_matmul128f<<<N_/32, 256, 0, stream>>>(bufY, W2, bufH, ss, x, xres,
                                          nullptr, nullptr, nullptr, nullptr);
  k_gcn_agg2<<<AGG_BLOCKS, 256, 0, stream>>>(bufH, ro, csr, dinv, b2, bufY, pbuf);
  k_bn_reduce<<<64, 256, 0, stream>>>(pbuf, g2, be2, ss);
  // L3: x2 = relu(bn(y2)) + x1 (in-place xres) ; h = x2 @ W3 ; y3 ; ss3
  k_matmul128f<<<N_/32, 256, 0, stream>>>(bufY, W3, bufH, ss, xres, xres,
                                          nullptr, nullptr, nullptr, nullptr);
  k_gcn_agg2<<<AGG_BLOCKS, 256, 0, stream>>>(bufH, ro, csr, dinv, b3, bufY, pbuf);
  k_bn_reduce<<<64, 256, 0, stream>>>(pbuf, g3, be3, ss);
  // GAT: x3 = relu(bn(y3)) + x2 (not materialized) ; h = x3 @ Wa ; al/ar in epilogue
  k_matmul128f<<<N_/32, 256, 0, stream>>>(bufY, Wa, bufH, ss, xres, nullptr,
                                          a_src, a_dst, al, ar);
  k_gat_agg2<<<AGG_BLOCKS, 256, 0, stream>>>(bufH, ro, csr, al, ar, ba, bufY, pbuf);
  k_bn_reduce<<<64, 256, 0, stream>>>(pbuf, ga, bea, ss);
  // pool with fused bn+relu
  k_pool2<<<G_, 256, 0, stream>>>(bufY, gstart, ss, pooled);
  // MLP
  k_gemm<<<dim3(NHID_/64, G_/64), 256, 0, stream>>>(pooled, Wl1, bl1, m1, G_, D_, NHID_, 1);
  k_gemm<<<dim3(NHID_/64, G_/64), 256, 0, stream>>>(m1, Wl2, bl2, m2, G_, NHID_, NHID_, 1);
  k_gemm<<<dim3(NHID_/64, G_/64), 256, 0, stream>>>(m2, Wl3, bl3, m1, G_, NHID_, NHID_, 1);
  k_gemm<<<dim3(NOUT_/64, G_/64), 256, 0, stream>>>(m1, Wl4, bl4, m4, G_, NHID_, NOUT_, 0);
  k_layernorm<<<G_, 256, 0, stream>>>(m4, gln, bln, out);
}

// Round 3
// 737.945 us; speedup vs baseline: 1.4939x; 1.2053x over previous
//
#include <hip/hip_runtime.h>
#include <cstdint>
#include <cstddef>

#define CDIV(a,b) (((a)+(b)-1)/(b))

constexpr int N_ = 100000;
constexpr int E_ = 600000;
constexpr int D_ = 128;
constexpr int G_ = 2048;
constexpr int NHID_ = 512;
constexpr int NOUT_ = 768;
constexpr float EPS_ = 1e-5f;
constexpr int AGG_BLOCKS = 2048;

typedef short bf16x8 __attribute__((ext_vector_type(8)));   // 8 bf16 (guide §3)
typedef float f32x4 __attribute__((ext_vector_type(4)));

__device__ __forceinline__ float wave_sum(float v){
#pragma unroll
  for (int m = 32; m; m >>= 1) v += __shfl_xor(v, m, 64);
  return v;
}
__device__ __forceinline__ float lrelu02(float v){ return v > 0.f ? v : 0.2f * v; }
__device__ __forceinline__ short f2bf(float f){
  unsigned u = __float_as_uint(f);
  u += 0x7FFF + ((u >> 16) & 1);   // round-to-nearest-even
  return (short)(u >> 16);
}

// ---------------- CSR build ----------------
__global__ void k_count(const int* __restrict__ dst, int* __restrict__ cnt){
  int e = blockIdx.x * 256 + threadIdx.x;
  if (e < E_) atomicAdd(&cnt[dst[e]], 1);
}

__global__ void k_dinv(const int* __restrict__ cnt, float* __restrict__ dinv){
  int i = blockIdx.x * 256 + threadIdx.x;
  if (i < N_) dinv[i] = rsqrtf((float)(cnt[i] + 1));
}

__global__ void k_scan1(const int* __restrict__ cnt, int* __restrict__ ro, int* __restrict__ bs){
  __shared__ int s[256];
  int tid = threadIdx.x;
  int i = blockIdx.x * 256 + tid;
  int v = (i < N_) ? cnt[i] : 0;
  s[tid] = v; __syncthreads();
  for (int off = 1; off < 256; off <<= 1){
    int add = (tid >= off) ? s[tid - off] : 0;
    __syncthreads();
    s[tid] += add;
    __syncthreads();
  }
  if (i < N_) ro[i] = s[tid] - v;
  if (tid == 255) bs[blockIdx.x] = s[255];
}

__global__ void k_scan2(int* __restrict__ bs, int nb){
  if (threadIdx.x == 0 && blockIdx.x == 0){
    int run = 0;
    for (int b = 0; b < nb; ++b){ int t = bs[b]; bs[b] = run; run += t; }
  }
}

__global__ void k_scan3(int* __restrict__ ro, const int* __restrict__ bs){
  int i = blockIdx.x * 256 + threadIdx.x;
  if (i < N_) ro[i] += bs[i >> 8];
  if (i == N_) ro[N_] = E_;
}

__global__ void k_fill(const int* __restrict__ src, const int* __restrict__ dst,
                       const int* __restrict__ ro, int* __restrict__ cur, int* __restrict__ csr){
  int e = blockIdx.x * 256 + threadIdx.x;
  if (e < E_){
    int d = dst[e];
    int p = atomicAdd(&cur[d], 1);
    csr[ro[d] + p] = src[e];
  }
}

__global__ void k_bounds(const int* __restrict__ batch, int* __restrict__ gs){
  int g = blockIdx.x * 256 + threadIdx.x;
  if (g > G_) return;
  int lo = 0, hi = N_;
  while (lo < hi){ int mid = (lo + hi) >> 1; if (batch[mid] < g) lo = mid + 1; else hi = mid; }
  gs[g] = lo;
}

// ---------------- W prep: pack W[128][128] f32 -> fragment-ordered bf16 ----------------
// Flat layout: for col c, kstep t, group g: 8 bf16, elem j -> W[t*32 + (j>>2)*16 + g*4 + (j&3)][c]
__global__ void k_wprep(const float* __restrict__ W, short* __restrict__ Wt){
  int i = blockIdx.x * 256 + threadIdx.x;
  if (i >= 128 * 16) return;
  int c = i >> 4, tg = i & 15, t = tg >> 2, g = tg & 3;
  short* o = Wt + (size_t)i * 8;
#pragma unroll
  for (int j = 0; j < 8; ++j){
    int k = t * 32 + (j >> 2) * 16 + g * 4 + (j & 3);
    o[j] = f2bf(W[(size_t)k * 128 + c]);
  }
}

// ---------------- MFMA node matmul: Y[N,128] = T(X) @ W ----------------
// T(v) = ss ? relu(v*sc+sh) (+res) : v ; optionally write T(X) to xnew
// optional epilogue: al/ar = Y . a_src / a_dst
__global__ __launch_bounds__(256) void k_mm_mfma(const float* __restrict__ X,
                                                 const short* __restrict__ Wt,
                                                 float* __restrict__ Y,
                                                 const float* __restrict__ ss,
                                                 const float* __restrict__ res,
                                                 float* __restrict__ xnew,
                                                 const float* __restrict__ asrc,
                                                 const float* __restrict__ adst,
                                                 float* __restrict__ al_out,
                                                 float* __restrict__ ar_out){
  int lane = threadIdx.x & 63, wid = threadIdx.x >> 6;
  int rw0 = blockIdx.x * 64 + wid * 16;
  int cl = lane & 15, g = lane >> 4;
  int arow = rw0 + cl;
  int kbase = g * 4;
  bool rvalid = arow < N_;

  f32x4 acc[8];
#pragma unroll
  for (int j = 0; j < 8; ++j) acc[j] = (f32x4){0.f, 0.f, 0.f, 0.f};

#pragma unroll
  for (int t = 0; t < 4; ++t){
    float4 va = make_float4(0.f,0.f,0.f,0.f), vb = va;
    int f0 = t * 32 + kbase;
    if (rvalid){
      va = *(const float4*)&X[(size_t)arow * 128 + f0];
      vb = *(const float4*)&X[(size_t)arow * 128 + f0 + 16];
    }
    if (ss){
      float4 sca = *(const float4*)&ss[f0],       sha = *(const float4*)&ss[128 + f0];
      float4 scb = *(const float4*)&ss[f0 + 16],  shb = *(const float4*)&ss[128 + f0 + 16];
      va.x = fmaxf(va.x*sca.x+sha.x, 0.f); va.y = fmaxf(va.y*sca.y+sha.y, 0.f);
      va.z = fmaxf(va.z*sca.z+sha.z, 0.f); va.w = fmaxf(va.w*sca.w+sha.w, 0.f);
      vb.x = fmaxf(vb.x*scb.x+shb.x, 0.f); vb.y = fmaxf(vb.y*scb.y+shb.y, 0.f);
      vb.z = fmaxf(vb.z*scb.z+shb.z, 0.f); vb.w = fmaxf(vb.w*scb.w+shb.w, 0.f);
      if (res && rvalid){
        float4 ra = *(const float4*)&res[(size_t)arow * 128 + f0];
        float4 rb = *(const float4*)&res[(size_t)arow * 128 + f0 + 16];
        va.x += ra.x; va.y += ra.y; va.z += ra.z; va.w += ra.w;
        vb.x += rb.x; vb.y += rb.y; vb.z += rb.z; vb.w += rb.w;
      }
      if (xnew && rvalid){
        *(float4*)&xnew[(size_t)arow * 128 + f0] = va;
        *(float4*)&xnew[(size_t)arow * 128 + f0 + 16] = vb;
      }
    }
    bf16x8 af;
    af[0]=f2bf(va.x); af[1]=f2bf(va.y); af[2]=f2bf(va.z); af[3]=f2bf(va.w);
    af[4]=f2bf(vb.x); af[5]=f2bf(vb.y); af[6]=f2bf(vb.z); af[7]=f2bf(vb.w);
#pragma unroll
    for (int j = 0; j < 8; ++j){
      int c = j * 16 + cl;
      bf16x8 bf = *(const bf16x8*)(Wt + ((size_t)c * 16 + t * 4 + g) * 8);
      acc[j] = __builtin_amdgcn_mfma_f32_16x16x32_bf16(af, bf, acc[j], 0, 0, 0);
    }
  }

  // store D: row = rw0 + g*4 + r, col = j*16 + cl
#pragma unroll
  for (int r = 0; r < 4; ++r){
    int row = rw0 + g * 4 + r;
    if (row < N_){
#pragma unroll
      for (int j = 0; j < 8; ++j)
        Y[(size_t)row * 128 + j * 16 + cl] = acc[j][r];
    }
  }

  if (al_out){
    float pal[4] = {0,0,0,0}, par[4] = {0,0,0,0};
#pragma unroll
    for (int j = 0; j < 8; ++j){
      float as_ = asrc[j * 16 + cl], ad_ = adst[j * 16 + cl];
#pragma unroll
      for (int r = 0; r < 4; ++r){ pal[r] += acc[j][r] * as_; par[r] += acc[j][r] * ad_; }
    }
#pragma unroll
    for (int m = 1; m < 16; m <<= 1)
#pragma unroll
      for (int r = 0; r < 4; ++r){
        pal[r] += __shfl_xor(pal[r], m, 64);
        par[r] += __shfl_xor(par[r], m, 64);
      }
    if (cl == 0){
#pragma unroll
      for (int r = 0; r < 4; ++r){
        int row = rw0 + g * 4 + r;
        if (row < N_){ al_out[row] = pal[r]; ar_out[row] = par[r]; }
      }
    }
  }
}

// ---------------- GCN aggregate (fused bias + BN stats partials) ----------------
__global__ __launch_bounds__(256) void k_gcn_agg2(const float* __restrict__ h, const int* __restrict__ ro,
                          const int* __restrict__ csr, const float* __restrict__ dinv,
                          const float* __restrict__ bias, float* __restrict__ outb,
                          float4* __restrict__ pbuf){
  int wid = threadIdx.x >> 6, lane = threadIdx.x & 63;
  const float2* h2 = (const float2*)h;
  float2 bb = ((const float2*)bias)[lane];
  float2 S = make_float2(0.f, 0.f), Q = make_float2(0.f, 0.f);
  for (int node = blockIdx.x * 4 + wid; node < N_; node += AGG_BLOCKS * 4){
    int s0 = ro[node], s1 = ro[node + 1];
    int deg = s1 - s0;
    float di = dinv[node];
    float2 hi = h2[(size_t)node * 64 + lane];
    float2 acc = make_float2(0.f, 0.f);
    if (deg <= 64){
      int sidx = 0; float wl = 0.f;
      if (lane < deg){ sidx = csr[s0 + lane]; wl = dinv[sidx]; }
      int j = 0;
      for (; j + 4 <= deg; j += 4){
        int sa = __shfl(sidx, j, 64),   sb = __shfl(sidx, j+1, 64);
        int sc = __shfl(sidx, j+2, 64), sd = __shfl(sidx, j+3, 64);
        float wa = __shfl(wl, j, 64),   wb = __shfl(wl, j+1, 64);
        float wc = __shfl(wl, j+2, 64), wd = __shfl(wl, j+3, 64);
        float2 va = h2[(size_t)sa*64+lane], vb = h2[(size_t)sb*64+lane];
        float2 vc = h2[(size_t)sc*64+lane], vd = h2[(size_t)sd*64+lane];
        acc.x += wa*va.x + wb*vb.x + wc*vc.x + wd*vd.x;
        acc.y += wa*va.y + wb*vb.y + wc*vc.y + wd*vd.y;
      }
      for (; j < deg; ++j){
        int s = __shfl(sidx, j, 64); float w = __shfl(wl, j, 64);
        float2 v = h2[(size_t)s*64+lane];
        acc.x += w*v.x; acc.y += w*v.y;
      }
    } else {
      for (int base = s0; base < s1; base += 64){
        int c = min(64, s1 - base);
        int sidx = 0; float wl = 0.f;
        if (lane < c){ sidx = csr[base + lane]; wl = dinv[sidx]; }
        for (int j = 0; j < c; ++j){
          int s = __shfl(sidx, j, 64); float w = __shfl(wl, j, 64);
          float2 v = h2[(size_t)s*64+lane];
          acc.x += w*v.x; acc.y += w*v.y;
        }
      }
    }
    float2 o;
    o.x = di * (acc.x + di * hi.x) + bb.x;
    o.y = di * (acc.y + di * hi.y) + bb.y;
    ((float2*)outb)[(size_t)node * 64 + lane] = o;
    S.x += o.x; S.y += o.y; Q.x += o.x*o.x; Q.y += o.y*o.y;
  }
  __shared__ float4 sred[4][64];
  sred[wid][lane] = make_float4(S.x, S.y, Q.x, Q.y);
  __syncthreads();
  if (wid == 0){
    float4 t = sred[0][lane];
    float4 u1 = sred[1][lane], u2 = sred[2][lane], u3 = sred[3][lane];
    t.x += u1.x + u2.x + u3.x;
    t.y += u1.y + u2.y + u3.y;
    t.z += u1.z + u2.z + u3.z;
    t.w += u1.w + u2.w + u3.w;
    pbuf[(size_t)blockIdx.x * 64 + lane] = t;
  }
}

// ---------------- GAT aggregate (no-max softmax, fused bias + stats) ----------------
__global__ __launch_bounds__(256) void k_gat_agg2(const float* __restrict__ h, const int* __restrict__ ro,
                          const int* __restrict__ csr, const float* __restrict__ al,
                          const float* __restrict__ ar, const float* __restrict__ bias,
                          float* __restrict__ outb, float4* __restrict__ pbuf){
  int wid = threadIdx.x >> 6, lane = threadIdx.x & 63;
  const float2* h2 = (const float2*)h;
  float2 bb = ((const float2*)bias)[lane];
  float2 S = make_float2(0.f, 0.f), Q = make_float2(0.f, 0.f);
  for (int node = blockIdx.x * 4 + wid; node < N_; node += AGG_BLOCKS * 4){
    int s0 = ro[node], s1 = ro[node + 1];
    int deg = s1 - s0;
    float ari = ar[node], ali = al[node];
    float pself = __expf(lrelu02(ali + ari));
    float2 hi = h2[(size_t)node * 64 + lane];
    float2 acc;
    if (deg <= 64){
      int sidx = 0; float p = 0.f;
      if (lane < deg){ sidx = csr[s0 + lane]; p = __expf(lrelu02(al[sidx] + ari)); }
      float invd = 1.f / (wave_sum(p) + pself);
      float wl = p * invd;
      float wsf = pself * invd;
      acc = make_float2(wsf * hi.x, wsf * hi.y);
      int j = 0;
      for (; j + 4 <= deg; j += 4){
        int sa = __shfl(sidx, j, 64),   sb = __shfl(sidx, j+1, 64);
        int sc = __shfl(sidx, j+2, 64), sd = __shfl(sidx, j+3, 64);
        float wa = __shfl(wl, j, 64),   wb = __shfl(wl, j+1, 64);
        float wc = __shfl(wl, j+2, 64), wd = __shfl(wl, j+3, 64);
        float2 va = h2[(size_t)sa*64+lane], vb = h2[(size_t)sb*64+lane];
        float2 vc = h2[(size_t)sc*64+lane], vd = h2[(size_t)sd*64+lane];
        acc.x += wa*va.x + wb*vb.x + wc*vc.x + wd*vd.x;
        acc.y += wa*va.y + wb*vb.y + wc*vc.y + wd*vd.y;
      }
      for (; j < deg; ++j){
        int s = __shfl(sidx, j, 64); float w = __shfl(wl, j, 64);
        float2 v = h2[(size_t)s*64+lane];
        acc.x += w*v.x; acc.y += w*v.y;
      }
    } else {
      float denom = pself;
      for (int base = s0; base < s1; base += 64){
        int c = min(64, s1 - base);
        float p = 0.f;
        if (lane < c) p = __expf(lrelu02(al[csr[base + lane]] + ari));
        denom += wave_sum(p);
      }
      float invd = 1.f / denom;
      float wsf = pself * invd;
      acc = make_float2(wsf * hi.x, wsf * hi.y);
      for (int base = s0; base < s1; base += 64){
        int c = min(64, s1 - base);
        int sidx = 0; float wl = 0.f;
        if (lane < c){ sidx = csr[base + lane]; wl = __expf(lrelu02(al[sidx] + ari)) * invd; }
        for (int j = 0; j < c; ++j){
          int s = __shfl(sidx, j, 64); float w = __shfl(wl, j, 64);
          float2 v = h2[(size_t)s*64+lane];
          acc.x += w*v.x; acc.y += w*v.y;
        }
      }
    }
    float2 o = make_float2(acc.x + bb.x, acc.y + bb.y);
    ((float2*)outb)[(size_t)node * 64 + lane] = o;
    S.x += o.x; S.y += o.y; Q.x += o.x*o.x; Q.y += o.y*o.y;
  }
  __shared__ float4 sred[4][64];
  sred[wid][lane] = make_float4(S.x, S.y, Q.x, Q.y);
  __syncthreads();
  if (wid == 0){
    float4 t = sred[0][lane];
    float4 u1 = sred[1][lane], u2 = sred[2][lane], u3 = sred[3][lane];
    t.x += u1.x + u2.x + u3.x;
    t.y += u1.y + u2.y + u3.y;
    t.z += u1.z + u2.z + u3.z;
    t.w += u1.w + u2.w + u3.w;
    pbuf[(size_t)blockIdx.x * 64 + lane] = t;
  }
}

// ---------------- BN partial reduce -> scale/shift ----------------
__global__ void k_bn_reduce(const float4* __restrict__ pbuf, const float* __restrict__ g,
                            const float* __restrict__ be, float* __restrict__ ss){
  int c = blockIdx.x;
  float4 a = make_float4(0.f, 0.f, 0.f, 0.f);
  for (int r = threadIdx.x; r < AGG_BLOCKS; r += 256){
    float4 v = pbuf[(size_t)r * 64 + c];
    a.x += v.x; a.y += v.y; a.z += v.z; a.w += v.w;
  }
  __shared__ float4 s[256];
  s[threadIdx.x] = a; __syncthreads();
  for (int off = 128; off; off >>= 1){
    if (threadIdx.x < off){
      float4 o = s[threadIdx.x + off];
      s[threadIdx.x].x += o.x; s[threadIdx.x].y += o.y;
      s[threadIdx.x].z += o.z; s[threadIdx.x].w += o.w;
    }
    __syncthreads();
  }
  if (threadIdx.x == 0){
    float4 t = s[0];
    float inv_n = 1.f / (float)N_;
    float mean0 = t.x * inv_n, mean1 = t.y * inv_n;
    float var0 = fmaxf(t.z * inv_n - mean0 * mean0, 0.f);
    float var1 = fmaxf(t.w * inv_n - mean1 * mean1, 0.f);
    float sc0 = g[2*c]   * rsqrtf(var0 + EPS_);
    float sc1 = g[2*c+1] * rsqrtf(var1 + EPS_);
    ss[2*c] = sc0; ss[2*c+1] = sc1;
    ss[128 + 2*c] = be[2*c] - mean0 * sc0;
    ss[128 + 2*c+1] = be[2*c+1] - mean1 * sc1;
  }
}

// ---------------- pool with fused BN-apply+relu ----------------
__global__ void k_pool2(const float* __restrict__ xn, const int* __restrict__ gs,
                        const float* __restrict__ ss, float* __restrict__ pooled){
  int g = blockIdx.x, f = threadIdx.x & 127, half = threadIdx.x >> 7;
  int s = gs[g], e = gs[g + 1];
  float sc = ss[f], sh = ss[128 + f];
  float a = 0.f;
  for (int n = s + half; n < e; n += 2)
    a += fmaxf(xn[(size_t)n * 128 + f] * sc + sh, 0.f);
  __shared__ float red[256];
  red[threadIdx.x] = a; __syncthreads();
  if (half == 0) pooled[(size_t)g * 128 + f] = red[f] + red[128 + f];
}

// ---------------- generic MLP GEMM ----------------
__global__ __launch_bounds__(256) void k_gemm(const float* __restrict__ A, const float* __restrict__ W,
                                              const float* __restrict__ bias, float* __restrict__ C,
                                              int M, int K, int Nc, int relu){
  __shared__ float As[64][17];
  __shared__ float Ws[16][64];
  int tid = threadIdx.x;
  int ty = tid >> 4, tx = tid & 15;
  int rb = blockIdx.y * 64, cb = blockIdx.x * 64;
  float acc[4][4] = {};
  for (int k0 = 0; k0 < K; k0 += 16){
    {
      int r = tid >> 2, kq = tid & 3;
      float4 v = *(const float4*)&A[(size_t)(rb + r) * K + k0 + kq * 4];
      As[r][kq*4+0] = v.x; As[r][kq*4+1] = v.y; As[r][kq*4+2] = v.z; As[r][kq*4+3] = v.w;
    }
    {
      int kk = tid >> 4, cq = tid & 15;
      float4 v = *(const float4*)&W[(size_t)(k0 + kk) * Nc + cb + cq * 4];
      *(float4*)&Ws[kk][cq * 4] = v;
    }
    __syncthreads();
#pragma unroll
    for (int k = 0; k < 16; ++k){
      float a0 = As[ty*4+0][k], a1 = As[ty*4+1][k], a2 = As[ty*4+2][k], a3 = As[ty*4+3][k];
      float b0 = Ws[k][tx], b1 = Ws[k][tx+16], b2 = Ws[k][tx+32], b3 = Ws[k][tx+48];
      acc[0][0] += a0*b0; acc[0][1] += a0*b1; acc[0][2] += a0*b2; acc[0][3] += a0*b3;
      acc[1][0] += a1*b0; acc[1][1] += a1*b1; acc[1][2] += a1*b2; acc[1][3] += a1*b3;
      acc[2][0] += a2*b0; acc[2][1] += a2*b1; acc[2][2] += a2*b2; acc[2][3] += a2*b3;
      acc[3][0] += a3*b0; acc[3][1] += a3*b1; acc[3][2] += a3*b2; acc[3][3] += a3*b3;
    }
    __syncthreads();
  }
#pragma unroll
  for (int i = 0; i < 4; ++i)
#pragma unroll
    for (int j = 0; j < 4; ++j){
      int c = cb + tx + 16 * j;
      float v = acc[i][j] + bias[c];
      if (relu) v = fmaxf(v, 0.f);
      C[(size_t)(rb + ty*4 + i) * Nc + c] = v;
    }
}

// ---------------- final layernorm over 768 ----------------
__global__ void k_layernorm(const float* __restrict__ xin, const float* __restrict__ g,
                            const float* __restrict__ b, float* __restrict__ out){
  __shared__ float red[8];
  int row = blockIdx.x, tid = threadIdx.x;
  float v0 = xin[(size_t)row*768 + tid];
  float v1 = xin[(size_t)row*768 + tid + 256];
  float v2 = xin[(size_t)row*768 + tid + 512];
  float s = v0 + v1 + v2;
  float q = v0*v0 + v1*v1 + v2*v2;
  s = wave_sum(s); q = wave_sum(q);
  int wid = tid >> 6;
  if ((tid & 63) == 0){ red[wid] = s; red[4 + wid] = q; }
  __syncthreads();
  if (tid == 0){
    float ts = red[0] + red[1] + red[2] + red[3];
    float tq = red[4] + red[5] + red[6] + red[7];
    float mean = ts / 768.f;
    float var = tq / 768.f - mean * mean;
    red[0] = mean; red[1] = rsqrtf(fmaxf(var, 0.f) + EPS_);
  }
  __syncthreads();
  float mean = red[0], inv = red[1];
  out[(size_t)row*768 + tid]       = (v0 - mean) * inv * g[tid]       + b[tid];
  out[(size_t)row*768 + tid + 256] = (v1 - mean) * inv * g[tid + 256] + b[tid + 256];
  out[(size_t)row*768 + tid + 512] = (v2 - mean) * inv * g[tid + 512] + b[tid + 512];
}

extern "C" void kernel_launch(void* const* d_in, const int* in_sizes, int n_in,
                              void* d_out, int out_size, void* d_ws, size_t ws_size,
                              hipStream_t stream){
  const float* x     = (const float*)d_in[0];
  const int*   ei    = (const int*)d_in[1];
  const int*   src   = ei;
  const int*   dst   = ei + E_;
  const int*   batch = (const int*)d_in[2];
  const float* W1 = (const float*)d_in[3];  const float* b1 = (const float*)d_in[4];
  const float* W2 = (const float*)d_in[5];  const float* b2 = (const float*)d_in[6];
  const float* W3 = (const float*)d_in[7];  const float* b3 = (const float*)d_in[8];
  const float* Wa = (const float*)d_in[9];  const float* ba = (const float*)d_in[10];
  const float* a_src = (const float*)d_in[11]; const float* a_dst = (const float*)d_in[12];
  const float* g1 = (const float*)d_in[13]; const float* be1 = (const float*)d_in[14];
  const float* g2 = (const float*)d_in[15]; const float* be2 = (const float*)d_in[16];
  const float* g3 = (const float*)d_in[17]; const float* be3 = (const float*)d_in[18];
  const float* ga = (const float*)d_in[19]; const float* bea = (const float*)d_in[20];
  const float* Wl1 = (const float*)d_in[21]; const float* bl1 = (const float*)d_in[22];
  const float* Wl2 = (const float*)d_in[23]; const float* bl2 = (const float*)d_in[24];
  const float* Wl3 = (const float*)d_in[25]; const float* bl3 = (const float*)d_in[26];
  const float* Wl4 = (const float*)d_in[27]; const float* bl4 = (const float*)d_in[28];
  const float* gln = (const float*)d_in[29]; const float* bln = (const float*)d_in[30];
  float* out = (float*)d_out;

  char* base = (char*)d_ws;
  size_t off = 0;
  auto alloc = [&](size_t bytes)->char*{
    char* p = base + off;
    off += (bytes + 255) & ~(size_t)255;
    return p;
  };
  int*   cnt    = (int*)  alloc((size_t)N_ * 4);
  float* dinv   = (float*)alloc((size_t)N_ * 4);
  int*   ro     = (int*)  alloc((size_t)(N_ + 1) * 4);
  int*   bs     = (int*)  alloc(512 * 4);
  int*   cur    = (int*)  alloc((size_t)N_ * 4);
  int*   csr    = (int*)  alloc((size_t)E_ * 4);
  int*   gstart = (int*)  alloc((size_t)(G_ + 1) * 4);
  float* al     = (float*)alloc((size_t)N_ * 4);
  float* ar     = (float*)alloc((size_t)N_ * 4);
  float* ss     = (float*)alloc(256 * 4);
  float4* pbuf  = (float4*)alloc((size_t)AGG_BLOCKS * 64 * 16);
  short* wt1    = (short*)alloc((size_t)128 * 128 * 2);
  short* wt2    = (short*)alloc((size_t)128 * 128 * 2);
  short* wt3    = (short*)alloc((size_t)128 * 128 * 2);
  short* wta    = (short*)alloc((size_t)128 * 128 * 2);
  float* bufH   = (float*)alloc((size_t)N_ * D_ * 4);
  float* bufY   = (float*)alloc((size_t)N_ * D_ * 4);
  float* xres   = (float*)alloc((size_t)N_ * D_ * 4);
  float* pooled = (float*)alloc((size_t)G_ * D_ * 4);
  float* m1     = (float*)alloc((size_t)G_ * NHID_ * 4);
  float* m2     = (float*)alloc((size_t)G_ * NHID_ * 4);
  float* m4     = (float*)alloc((size_t)G_ * NOUT_ * 4);
  (void)ws_size; (void)in_sizes; (void)n_in; (void)out_size;

  const int nbE = CDIV(E_, 256), nbN = CDIV(N_, 256);
  const int MMB = CDIV(N_, 64);

  hipMemsetAsync(cnt, 0, (size_t)N_ * 4, stream);
  k_count<<<nbE, 256, 0, stream>>>(dst, cnt);
  k_dinv<<<nbN, 256, 0, stream>>>(cnt, dinv);
  k_scan1<<<nbN, 256, 0, stream>>>(cnt, ro, bs);
  k_scan2<<<1, 64, 0, stream>>>(bs, nbN);
  k_scan3<<<CDIV(N_ + 1, 256), 256, 0, stream>>>(ro, bs);
  hipMemsetAsync(cur, 0, (size_t)N_ * 4, stream);
  k_fill<<<nbE, 256, 0, stream>>>(src, dst, ro, cur, csr);
  k_bounds<<<CDIV(G_ + 1, 256), 256, 0, stream>>>(batch, gstart);
  k_wprep<<<8, 256, 0, stream>>>(W1, wt1);
  k_wprep<<<8, 256, 0, stream>>>(W2, wt2);
  k_wprep<<<8, 256, 0, stream>>>(W3, wt3);
  k_wprep<<<8, 256, 0, stream>>>(Wa, wta);

  // L1
  k_mm_mfma<<<MMB, 256, 0, stream>>>(x, wt1, bufH, nullptr, nullptr, nullptr,
                                     nullptr, nullptr, nullptr, nullptr);
  k_gcn_agg2<<<AGG_BLOCKS, 256, 0, stream>>>(bufH, ro, csr, dinv, b1, bufY, pbuf);
  k_bn_reduce<<<64, 256, 0, stream>>>(pbuf, g1, be1, ss);
  // L2
  k_mm_mfma<<<MMB, 256, 0, stream>>>(bufY, wt2, bufH, ss, x, xres,
                                     nullptr, nullptr, nullptr, nullptr);
  k_gcn_agg2<<<AGG_BLOCKS, 256, 0, stream>>>(bufH, ro, csr, dinv, b2, bufY, pbuf);
  k_bn_reduce<<<64, 256, 0, stream>>>(pbuf, g2, be2, ss);
  // L3
  k_mm_mfma<<<MMB, 256, 0, stream>>>(bufY, wt3, bufH, ss, xres, xres,
                                     nullptr, nullptr, nullptr, nullptr);
  k_gcn_agg2<<<AGG_BLOCKS, 256, 0, stream>>>(bufH, ro, csr, dinv, b3, bufY, pbuf);
  k_bn_reduce<<<64, 256, 0, stream>>>(pbuf, g3, be3, ss);
  // GAT
  k_mm_mfma<<<MMB, 256, 0, stream>>>(bufY, wta, bufH, ss, xres, nullptr,
                                     a_src, a_dst, al, ar);
  k_gat_agg2<<<AGG_BLOCKS, 256, 0, stream>>>(bufH, ro, csr, al, ar, ba, bufY, pbuf);
  k_bn_reduce<<<64, 256, 0, stream>>>(pbuf, ga, bea, ss);
  // pool
  k_pool2<<<G_, 256, 0, stream>>>(bufY, gstart, ss, pooled);
  // MLP
  k_gemm<<<dim3(NHID_/64, G_/64), 256, 0, stream>>>(pooled, Wl1, bl1, m1, G_, D_, NHID_, 1);
  k_gemm<<<dim3(NHID_/64, G_/64), 256, 0, stream>>>(m1, Wl2, bl2, m2, G_, NHID_, NHID_, 1);
  k_gemm<<<dim3(NHID_/64, G_/64), 256, 0, stream>>>(m2, Wl3, bl3, m1, G_, NHID_, NHID_, 1);
  k_gemm<<<dim3(NOUT_/64, G_/64), 256, 0, stream>>>(m1, Wl4, bl4, m4, G_, NHID_, NOUT_, 0);
  k_layernorm<<<G_, 256, 0, stream>>>(m4, gln, bln, out);
}

// Round 4
// 597.832 us; speedup vs baseline: 1.8440x; 1.2344x over previous
//
#include <hip/hip_runtime.h>
#include <cstdint>
#include <cstddef>

#define CDIV(a,b) (((a)+(b)-1)/(b))

constexpr int N_ = 100000;
constexpr int E_ = 600000;
constexpr int D_ = 128;
constexpr int G_ = 2048;
constexpr int NHID_ = 512;
constexpr int NOUT_ = 768;
constexpr float EPS_ = 1e-5f;
constexpr int AGG_BLOCKS = 2048;

typedef short bf16x8 __attribute__((ext_vector_type(8)));
typedef float f32x4 __attribute__((ext_vector_type(4)));

__device__ __forceinline__ float wave_sum(float v){
#pragma unroll
  for (int m = 32; m; m >>= 1) v += __shfl_xor(v, m, 64);
  return v;
}
__device__ __forceinline__ float lrelu02(float v){ return v > 0.f ? v : 0.2f * v; }
__device__ __forceinline__ unsigned short f2bf(float f){
  unsigned u = __float_as_uint(f);
  u += 0x7FFF + ((u >> 16) & 1);
  return (unsigned short)(u >> 16);
}
__device__ __forceinline__ float bflo(unsigned u){ return __uint_as_float(u << 16); }
__device__ __forceinline__ float bfhi(unsigned u){ return __uint_as_float(u & 0xFFFF0000u); }

// ---------------- CSR build ----------------
__global__ void k_count(const int* __restrict__ dst, int* __restrict__ cnt){
  int e = blockIdx.x * 256 + threadIdx.x;
  if (e < E_) atomicAdd(&cnt[dst[e]], 1);
}

__global__ void k_dinv(const int* __restrict__ cnt, float* __restrict__ dinv){
  int i = blockIdx.x * 256 + threadIdx.x;
  if (i < N_) dinv[i] = rsqrtf((float)(cnt[i] + 1));
}

__global__ void k_scan1(const int* __restrict__ cnt, int* __restrict__ ro, int* __restrict__ bs){
  __shared__ int s[256];
  int tid = threadIdx.x;
  int i = blockIdx.x * 256 + tid;
  int v = (i < N_) ? cnt[i] : 0;
  s[tid] = v; __syncthreads();
  for (int off = 1; off < 256; off <<= 1){
    int add = (tid >= off) ? s[tid - off] : 0;
    __syncthreads();
    s[tid] += add;
    __syncthreads();
  }
  if (i < N_) ro[i] = s[tid] - v;
  if (tid == 255) bs[blockIdx.x] = s[255];
}

__global__ void k_scan2(int* __restrict__ bs, int nb){
  __shared__ int s[512];
  int t = threadIdx.x;
  int v = (t < nb) ? bs[t] : 0;
  s[t] = v; __syncthreads();
  for (int off = 1; off < 512; off <<= 1){
    int a = (t >= off) ? s[t - off] : 0;
    __syncthreads();
    s[t] += a;
    __syncthreads();
  }
  if (t < nb) bs[t] = s[t] - v;   // exclusive block offsets
}

__global__ void k_scan3(int* __restrict__ ro, const int* __restrict__ bs){
  int i = blockIdx.x * 256 + threadIdx.x;
  if (i < N_) ro[i] += bs[i >> 8];
  if (i == N_) ro[N_] = E_;
}

__global__ void k_fill(const int* __restrict__ src, const int* __restrict__ dst,
                       const int* __restrict__ ro, int* __restrict__ cur, int* __restrict__ csr){
  int e = blockIdx.x * 256 + threadIdx.x;
  if (e < E_){
    int d = dst[e];
    int p = atomicAdd(&cur[d], 1);
    csr[ro[d] + p] = src[e];
  }
}

__global__ void k_bounds(const int* __restrict__ batch, int* __restrict__ gs){
  int g = blockIdx.x * 256 + threadIdx.x;
  if (g > G_) return;
  int lo = 0, hi = N_;
  while (lo < hi){ int mid = (lo + hi) >> 1; if (batch[mid] < g) lo = mid + 1; else hi = mid; }
  gs[g] = lo;
}

// ---------------- W prep: pack W[128][128] f32 -> fragment-ordered bf16 ----------------
__global__ void k_wprep(const float* __restrict__ W, short* __restrict__ Wt){
  int i = blockIdx.x * 256 + threadIdx.x;
  if (i >= 128 * 16) return;
  int c = i >> 4, tg = i & 15, t = tg >> 2, g = tg & 3;
  short* o = Wt + (size_t)i * 8;
#pragma unroll
  for (int j = 0; j < 8; ++j){
    int k = t * 32 + (j >> 2) * 16 + g * 4 + (j & 3);
    o[j] = (short)f2bf(W[(size_t)k * 128 + c]);
  }
}

// ---------------- MFMA node matmul ----------------
// hout (bf16-pair swizzled): uint u = jp*16+cl of row holds cols (32jp+cl, 32jp+cl+16)
// optional prescale (dinv) multiplies output rows before store (GCN trick).
__global__ __launch_bounds__(256) void k_mm_mfma(const float* __restrict__ X,
                                                 const short* __restrict__ Wt,
                                                 unsigned* __restrict__ hout,
                                                 const float* __restrict__ ss,
                                                 const float* __restrict__ res,
                                                 float* __restrict__ xnew,
                                                 const float* __restrict__ prescale,
                                                 const float* __restrict__ asrc,
                                                 const float* __restrict__ adst,
                                                 float* __restrict__ al_out,
                                                 float* __restrict__ ar_out){
  int lane = threadIdx.x & 63, wid = threadIdx.x >> 6;
  int rw0 = blockIdx.x * 64 + wid * 16;
  int cl = lane & 15, g = lane >> 4;
  int arow = rw0 + cl;
  int kbase = g * 4;
  bool rvalid = arow < N_;

  f32x4 acc[8];
#pragma unroll
  for (int j = 0; j < 8; ++j) acc[j] = (f32x4){0.f, 0.f, 0.f, 0.f};

#pragma unroll
  for (int t = 0; t < 4; ++t){
    float4 va = make_float4(0.f,0.f,0.f,0.f), vb = va;
    int f0 = t * 32 + kbase;
    if (rvalid){
      va = *(const float4*)&X[(size_t)arow * 128 + f0];
      vb = *(const float4*)&X[(size_t)arow * 128 + f0 + 16];
    }
    if (ss){
      float4 sca = *(const float4*)&ss[f0],       sha = *(const float4*)&ss[128 + f0];
      float4 scb = *(const float4*)&ss[f0 + 16],  shb = *(const float4*)&ss[128 + f0 + 16];
      va.x = fmaxf(va.x*sca.x+sha.x, 0.f); va.y = fmaxf(va.y*sca.y+sha.y, 0.f);
      va.z = fmaxf(va.z*sca.z+sha.z, 0.f); va.w = fmaxf(va.w*sca.w+sha.w, 0.f);
      vb.x = fmaxf(vb.x*scb.x+shb.x, 0.f); vb.y = fmaxf(vb.y*scb.y+shb.y, 0.f);
      vb.z = fmaxf(vb.z*scb.z+shb.z, 0.f); vb.w = fmaxf(vb.w*scb.w+shb.w, 0.f);
      if (res && rvalid){
        float4 ra = *(const float4*)&res[(size_t)arow * 128 + f0];
        float4 rb = *(const float4*)&res[(size_t)arow * 128 + f0 + 16];
        va.x += ra.x; va.y += ra.y; va.z += ra.z; va.w += ra.w;
        vb.x += rb.x; vb.y += rb.y; vb.z += rb.z; vb.w += rb.w;
      }
      if (xnew && rvalid){
        *(float4*)&xnew[(size_t)arow * 128 + f0] = va;
        *(float4*)&xnew[(size_t)arow * 128 + f0 + 16] = vb;
      }
    }
    bf16x8 af;
    af[0]=(short)f2bf(va.x); af[1]=(short)f2bf(va.y); af[2]=(short)f2bf(va.z); af[3]=(short)f2bf(va.w);
    af[4]=(short)f2bf(vb.x); af[5]=(short)f2bf(vb.y); af[6]=(short)f2bf(vb.z); af[7]=(short)f2bf(vb.w);
#pragma unroll
    for (int j = 0; j < 8; ++j){
      int c = j * 16 + cl;
      bf16x8 bf = *(const bf16x8*)(Wt + ((size_t)c * 16 + t * 4 + g) * 8);
      acc[j] = __builtin_amdgcn_mfma_f32_16x16x32_bf16(af, bf, acc[j], 0, 0, 0);
    }
  }

  // store: row = rw0 + g*4 + r; pack (acc[2jp][r], acc[2jp+1][r]) -> uint at jp*16+cl
#pragma unroll
  for (int r = 0; r < 4; ++r){
    int row = rw0 + g * 4 + r;
    if (row < N_){
      float psc = prescale ? prescale[row] : 1.f;
#pragma unroll
      for (int jp = 0; jp < 4; ++jp){
        unsigned lo = f2bf(acc[2*jp][r] * psc);
        unsigned hi = f2bf(acc[2*jp+1][r] * psc);
        hout[(size_t)row * 64 + jp * 16 + cl] = (hi << 16) | lo;
      }
    }
  }

  if (al_out){
    float pal[4] = {0,0,0,0}, par[4] = {0,0,0,0};
#pragma unroll
    for (int j = 0; j < 8; ++j){
      float as_ = asrc[j * 16 + cl], ad_ = adst[j * 16 + cl];
#pragma unroll
      for (int r = 0; r < 4; ++r){ pal[r] += acc[j][r] * as_; par[r] += acc[j][r] * ad_; }
    }
#pragma unroll
    for (int m = 1; m < 16; m <<= 1)
#pragma unroll
      for (int r = 0; r < 4; ++r){
        pal[r] += __shfl_xor(pal[r], m, 64);
        par[r] += __shfl_xor(par[r], m, 64);
      }
    if (cl == 0){
#pragma unroll
      for (int r = 0; r < 4; ++r){
        int row = rw0 + g * 4 + r;
        if (row < N_){ al_out[row] = pal[r]; ar_out[row] = par[r]; }
      }
    }
  }
}

// ---------------- GCN aggregate: h prescaled by dinv ----------------
// out_i[f] = dinv_i * (sum_s h'_s[f] + h'_i[f]) + b[f]
__global__ __launch_bounds__(256) void k_gcn_agg2(const unsigned* __restrict__ hbf, const int* __restrict__ ro,
                          const int* __restrict__ csr, const float* __restrict__ dinv,
                          const float* __restrict__ bias, float* __restrict__ outb,
                          float4* __restrict__ pbuf){
  int wid = threadIdx.x >> 6, lane = threadIdx.x & 63;
  int f0 = 32 * (lane >> 4) + (lane & 15), f1 = f0 + 16;
  float bb0 = bias[f0], bb1 = bias[f1];
  float S0 = 0.f, S1 = 0.f, Q0 = 0.f, Q1 = 0.f;
  for (int node = blockIdx.x * 4 + wid; node < N_; node += AGG_BLOCKS * 4){
    int s0 = ro[node], s1 = ro[node + 1];
    int deg = s1 - s0;
    float di = dinv[node];
    unsigned us = hbf[(size_t)node * 64 + lane];
    float a0 = bflo(us), a1 = bfhi(us);
    if (deg <= 64){
      int sidx = (lane < deg) ? csr[s0 + lane] : 0;
      int j = 0;
      for (; j + 4 <= deg; j += 4){
        int sa = __shfl(sidx, j, 64),   sb = __shfl(sidx, j+1, 64);
        int sc = __shfl(sidx, j+2, 64), sd = __shfl(sidx, j+3, 64);
        unsigned ua = hbf[(size_t)sa*64+lane], ub = hbf[(size_t)sb*64+lane];
        unsigned uc = hbf[(size_t)sc*64+lane], ud = hbf[(size_t)sd*64+lane];
        a0 += bflo(ua) + bflo(ub) + bflo(uc) + bflo(ud);
        a1 += bfhi(ua) + bfhi(ub) + bfhi(uc) + bfhi(ud);
      }
      for (; j < deg; ++j){
        int s = __shfl(sidx, j, 64);
        unsigned u = hbf[(size_t)s*64+lane];
        a0 += bflo(u); a1 += bfhi(u);
      }
    } else {
      for (int base = s0; base < s1; base += 64){
        int c = min(64, s1 - base);
        int sidx = (lane < c) ? csr[base + lane] : 0;
        for (int j = 0; j < c; ++j){
          int s = __shfl(sidx, j, 64);
          unsigned u = hbf[(size_t)s*64+lane];
          a0 += bflo(u); a1 += bfhi(u);
        }
      }
    }
    float o0 = di * a0 + bb0;
    float o1 = di * a1 + bb1;
    outb[(size_t)node * 128 + f0] = o0;
    outb[(size_t)node * 128 + f1] = o1;
    S0 += o0; S1 += o1; Q0 += o0*o0; Q1 += o1*o1;
  }
  __shared__ float4 sred[4][64];
  sred[wid][lane] = make_float4(S0, S1, Q0, Q1);
  __syncthreads();
  if (wid == 0){
    float4 t = sred[0][lane];
    float4 u1 = sred[1][lane], u2 = sred[2][lane], u3 = sred[3][lane];
    t.x += u1.x + u2.x + u3.x;
    t.y += u1.y + u2.y + u3.y;
    t.z += u1.z + u2.z + u3.z;
    t.w += u1.w + u2.w + u3.w;
    pbuf[(size_t)blockIdx.x * 64 + lane] = t;
  }
}

// ---------------- GAT aggregate (h unscaled bf16) ----------------
__global__ __launch_bounds__(256) void k_gat_agg2(const unsigned* __restrict__ hbf, const int* __restrict__ ro,
                          const int* __restrict__ csr, const float* __restrict__ al,
                          const float* __restrict__ ar, const float* __restrict__ bias,
                          float* __restrict__ outb, float4* __restrict__ pbuf){
  int wid = threadIdx.x >> 6, lane = threadIdx.x & 63;
  int f0 = 32 * (lane >> 4) + (lane & 15), f1 = f0 + 16;
  float bb0 = bias[f0], bb1 = bias[f1];
  float S0 = 0.f, S1 = 0.f, Q0 = 0.f, Q1 = 0.f;
  for (int node = blockIdx.x * 4 + wid; node < N_; node += AGG_BLOCKS * 4){
    int s0 = ro[node], s1 = ro[node + 1];
    int deg = s1 - s0;
    float ari = ar[node], ali = al[node];
    float pself = __expf(lrelu02(ali + ari));
    unsigned uself = hbf[(size_t)node * 64 + lane];
    float h0 = bflo(uself), h1 = bfhi(uself);
    float a0, a1;
    if (deg <= 64){
      int sidx = 0; float p = 0.f;
      if (lane < deg){ sidx = csr[s0 + lane]; p = __expf(lrelu02(al[sidx] + ari)); }
      float invd = 1.f / (wave_sum(p) + pself);
      float wl = p * invd;
      float wsf = pself * invd;
      a0 = wsf * h0; a1 = wsf * h1;
      int j = 0;
      for (; j + 4 <= deg; j += 4){
        int sa = __shfl(sidx, j, 64),   sb = __shfl(sidx, j+1, 64);
        int sc = __shfl(sidx, j+2, 64), sd = __shfl(sidx, j+3, 64);
        float wa = __shfl(wl, j, 64),   wb = __shfl(wl, j+1, 64);
        float wc = __shfl(wl, j+2, 64), wd = __shfl(wl, j+3, 64);
        unsigned ua = hbf[(size_t)sa*64+lane], ub = hbf[(size_t)sb*64+lane];
        unsigned uc = hbf[(size_t)sc*64+lane], ud = hbf[(size_t)sd*64+lane];
        a0 += wa*bflo(ua) + wb*bflo(ub) + wc*bflo(uc) + wd*bflo(ud);
        a1 += wa*bfhi(ua) + wb*bfhi(ub) + wc*bfhi(uc) + wd*bfhi(ud);
      }
      for (; j < deg; ++j){
        int s = __shfl(sidx, j, 64); float w = __shfl(wl, j, 64);
        unsigned u = hbf[(size_t)s*64+lane];
        a0 += w*bflo(u); a1 += w*bfhi(u);
      }
    } else {
      float denom = pself;
      for (int base = s0; base < s1; base += 64){
        int c = min(64, s1 - base);
        float p = 0.f;
        if (lane < c) p = __expf(lrelu02(al[csr[base + lane]] + ari));
        denom += wave_sum(p);
      }
      float invd = 1.f / denom;
      float wsf = pself * invd;
      a0 = wsf * h0; a1 = wsf * h1;
      for (int base = s0; base < s1; base += 64){
        int c = min(64, s1 - base);
        int sidx = 0; float wl = 0.f;
        if (lane < c){ sidx = csr[base + lane]; wl = __expf(lrelu02(al[sidx] + ari)) * invd; }
        for (int j = 0; j < c; ++j){
          int s = __shfl(sidx, j, 64); float w = __shfl(wl, j, 64);
          unsigned u = hbf[(size_t)s*64+lane];
          a0 += w*bflo(u); a1 += w*bfhi(u);
        }
      }
    }
    float o0 = a0 + bb0, o1 = a1 + bb1;
    outb[(size_t)node * 128 + f0] = o0;
    outb[(size_t)node * 128 + f1] = o1;
    S0 += o0; S1 += o1; Q0 += o0*o0; Q1 += o1*o1;
  }
  __shared__ float4 sred[4][64];
  sred[wid][lane] = make_float4(S0, S1, Q0, Q1);
  __syncthreads();
  if (wid == 0){
    float4 t = sred[0][lane];
    float4 u1 = sred[1][lane], u2 = sred[2][lane], u3 = sred[3][lane];
    t.x += u1.x + u2.x + u3.x;
    t.y += u1.y + u2.y + u3.y;
    t.z += u1.z + u2.z + u3.z;
    t.w += u1.w + u2.w + u3.w;
    pbuf[(size_t)blockIdx.x * 64 + lane] = t;
  }
}

// ---------------- BN partial reduce -> scale/shift (swizzled lane->feature map) ----------------
__global__ void k_bn_reduce(const float4* __restrict__ pbuf, const float* __restrict__ g,
                            const float* __restrict__ be, float* __restrict__ ss){
  int c = blockIdx.x;                       // lane index 0..63
  int f0 = 32 * (c >> 4) + (c & 15), f1 = f0 + 16;
  float4 a = make_float4(0.f, 0.f, 0.f, 0.f);
  for (int r = threadIdx.x; r < AGG_BLOCKS; r += 256){
    float4 v = pbuf[(size_t)r * 64 + c];
    a.x += v.x; a.y += v.y; a.z += v.z; a.w += v.w;
  }
  __shared__ float4 s[256];
  s[threadIdx.x] = a; __syncthreads();
  for (int off = 128; off; off >>= 1){
    if (threadIdx.x < off){
      float4 o = s[threadIdx.x + off];
      s[threadIdx.x].x += o.x; s[threadIdx.x].y += o.y;
      s[threadIdx.x].z += o.z; s[threadIdx.x].w += o.w;
    }
    __syncthreads();
  }
  if (threadIdx.x == 0){
    float4 t = s[0];
    float inv_n = 1.f / (float)N_;
    float mean0 = t.x * inv_n, mean1 = t.y * inv_n;
    float var0 = fmaxf(t.z * inv_n - mean0 * mean0, 0.f);
    float var1 = fmaxf(t.w * inv_n - mean1 * mean1, 0.f);
    float sc0 = g[f0] * rsqrtf(var0 + EPS_);
    float sc1 = g[f1] * rsqrtf(var1 + EPS_);
    ss[f0] = sc0; ss[f1] = sc1;
    ss[128 + f0] = be[f0] - mean0 * sc0;
    ss[128 + f1] = be[f1] - mean1 * sc1;
  }
}

// ---------------- pool with fused BN-apply+relu ----------------
__global__ void k_pool2(const float* __restrict__ xn, const int* __restrict__ gs,
                        const float* __restrict__ ss, float* __restrict__ pooled){
  int g = blockIdx.x, f = threadIdx.x & 127, half = threadIdx.x >> 7;
  int s = gs[g], e = gs[g + 1];
  float sc = ss[f], sh = ss[128 + f];
  float a = 0.f;
  for (int n = s + half; n < e; n += 2)
    a += fmaxf(xn[(size_t)n * 128 + f] * sc + sh, 0.f);
  __shared__ float red[256];
  red[threadIdx.x] = a; __syncthreads();
  if (half == 0) pooled[(size_t)g * 128 + f] = red[f] + red[128 + f];
}

// ---------------- generic MLP GEMM ----------------
__global__ __launch_bounds__(256) void k_gemm(const float* __restrict__ A, const float* __restrict__ W,
                                              const float* __restrict__ bias, float* __restrict__ C,
                                              int M, int K, int Nc, int relu){
  __shared__ float As[64][17];
  __shared__ float Ws[16][64];
  int tid = threadIdx.x;
  int ty = tid >> 4, tx = tid & 15;
  int rb = blockIdx.y * 64, cb = blockIdx.x * 64;
  float acc[4][4] = {};
  for (int k0 = 0; k0 < K; k0 += 16){
    {
      int r = tid >> 2, kq = tid & 3;
      float4 v = *(const float4*)&A[(size_t)(rb + r) * K + k0 + kq * 4];
      As[r][kq*4+0] = v.x; As[r][kq*4+1] = v.y; As[r][kq*4+2] = v.z; As[r][kq*4+3] = v.w;
    }
    {
      int kk = tid >> 4, cq = tid & 15;
      float4 v = *(const float4*)&W[(size_t)(k0 + kk) * Nc + cb + cq * 4];
      *(float4*)&Ws[kk][cq * 4] = v;
    }
    __syncthreads();
#pragma unroll
    for (int k = 0; k < 16; ++k){
      float a0 = As[ty*4+0][k], a1 = As[ty*4+1][k], a2 = As[ty*4+2][k], a3 = As[ty*4+3][k];
      float b0 = Ws[k][tx], b1 = Ws[k][tx+16], b2 = Ws[k][tx+32], b3 = Ws[k][tx+48];
      acc[0][0] += a0*b0; acc[0][1] += a0*b1; acc[0][2] += a0*b2; acc[0][3] += a0*b3;
      acc[1][0] += a1*b0; acc[1][1] += a1*b1; acc[1][2] += a1*b2; acc[1][3] += a1*b3;
      acc[2][0] += a2*b0; acc[2][1] += a2*b1; acc[2][2] += a2*b2; acc[2][3] += a2*b3;
      acc[3][0] += a3*b0; acc[3][1] += a3*b1; acc[3][2] += a3*b2; acc[3][3] += a3*b3;
    }
    __syncthreads();
  }
#pragma unroll
  for (int i = 0; i < 4; ++i)
#pragma unroll
    for (int j = 0; j < 4; ++j){
      int c = cb + tx + 16 * j;
      float v = acc[i][j] + bias[c];
      if (relu) v = fmaxf(v, 0.f);
      C[(size_t)(rb + ty*4 + i) * Nc + c] = v;
    }
}

// ---------------- final layernorm over 768 ----------------
__global__ void k_layernorm(const float* __restrict__ xin, const float* __restrict__ g,
                            const float* __restrict__ b, float* __restrict__ out){
  __shared__ float red[8];
  int row = blockIdx.x, tid = threadIdx.x;
  float v0 = xin[(size_t)row*768 + tid];
  float v1 = xin[(size_t)row*768 + tid + 256];
  float v2 = xin[(size_t)row*768 + tid + 512];
  float s = v0 + v1 + v2;
  float q = v0*v0 + v1*v1 + v2*v2;
  s = wave_sum(s); q = wave_sum(q);
  int wid = tid >> 6;
  if ((tid & 63) == 0){ red[wid] = s; red[4 + wid] = q; }
  __syncthreads();
  if (tid == 0){
    float ts = red[0] + red[1] + red[2] + red[3];
    float tq = red[4] + red[5] + red[6] + red[7];
    float mean = ts / 768.f;
    float var = tq / 768.f - mean * mean;
    red[0] = mean; red[1] = rsqrtf(fmaxf(var, 0.f) + EPS_);
  }
  __syncthreads();
  float mean = red[0], inv = red[1];
  out[(size_t)row*768 + tid]       = (v0 - mean) * inv * g[tid]       + b[tid];
  out[(size_t)row*768 + tid + 256] = (v1 - mean) * inv * g[tid + 256] + b[tid + 256];
  out[(size_t)row*768 + tid + 512] = (v2 - mean) * inv * g[tid + 512] + b[tid + 512];
}

extern "C" void kernel_launch(void* const* d_in, const int* in_sizes, int n_in,
                              void* d_out, int out_size, void* d_ws, size_t ws_size,
                              hipStream_t stream){
  const float* x     = (const float*)d_in[0];
  const int*   ei    = (const int*)d_in[1];
  const int*   src   = ei;
  const int*   dst   = ei + E_;
  const int*   batch = (const int*)d_in[2];
  const float* W1 = (const float*)d_in[3];  const float* b1 = (const float*)d_in[4];
  const float* W2 = (const float*)d_in[5];  const float* b2 = (const float*)d_in[6];
  const float* W3 = (const float*)d_in[7];  const float* b3 = (const float*)d_in[8];
  const float* Wa = (const float*)d_in[9];  const float* ba = (const float*)d_in[10];
  const float* a_src = (const float*)d_in[11]; const float* a_dst = (const float*)d_in[12];
  const float* g1 = (const float*)d_in[13]; const float* be1 = (const float*)d_in[14];
  const float* g2 = (const float*)d_in[15]; const float* be2 = (const float*)d_in[16];
  const float* g3 = (const float*)d_in[17]; const float* be3 = (const float*)d_in[18];
  const float* ga = (const float*)d_in[19]; const float* bea = (const float*)d_in[20];
  const float* Wl1 = (const float*)d_in[21]; const float* bl1 = (const float*)d_in[22];
  const float* Wl2 = (const float*)d_in[23]; const float* bl2 = (const float*)d_in[24];
  const float* Wl3 = (const float*)d_in[25]; const float* bl3 = (const float*)d_in[26];
  const float* Wl4 = (const float*)d_in[27]; const float* bl4 = (const float*)d_in[28];
  const float* gln = (const float*)d_in[29]; const float* bln = (const float*)d_in[30];
  float* out = (float*)d_out;

  char* base = (char*)d_ws;
  size_t off = 0;
  auto alloc = [&](size_t bytes)->char*{
    char* p = base + off;
    off += (bytes + 255) & ~(size_t)255;
    return p;
  };
  int*   cnt    = (int*)  alloc((size_t)N_ * 4);
  float* dinv   = (float*)alloc((size_t)N_ * 4);
  int*   ro     = (int*)  alloc((size_t)(N_ + 1) * 4);
  int*   bs     = (int*)  alloc(512 * 4);
  int*   cur    = (int*)  alloc((size_t)N_ * 4);
  int*   csr    = (int*)  alloc((size_t)E_ * 4);
  int*   gstart = (int*)  alloc((size_t)(G_ + 1) * 4);
  float* al     = (float*)alloc((size_t)N_ * 4);
  float* ar     = (float*)alloc((size_t)N_ * 4);
  float* ss     = (float*)alloc(256 * 4);
  float4* pbuf  = (float4*)alloc((size_t)AGG_BLOCKS * 64 * 16);
  short* wt1    = (short*)alloc((size_t)128 * 128 * 2);
  short* wt2    = (short*)alloc((size_t)128 * 128 * 2);
  short* wt3    = (short*)alloc((size_t)128 * 128 * 2);
  short* wta    = (short*)alloc((size_t)128 * 128 * 2);
  unsigned* bufH= (unsigned*)alloc((size_t)N_ * 64 * 4);   // bf16-pair swizzled h
  float* bufY   = (float*)alloc((size_t)N_ * D_ * 4);
  float* xres   = (float*)alloc((size_t)N_ * D_ * 4);
  float* pooled = (float*)alloc((size_t)G_ * D_ * 4);
  float* m1     = (float*)alloc((size_t)G_ * NHID_ * 4);
  float* m2     = (float*)alloc((size_t)G_ * NHID_ * 4);
  float* m4     = (float*)alloc((size_t)G_ * NOUT_ * 4);
  (void)ws_size; (void)in_sizes; (void)n_in; (void)out_size;

  const int nbE = CDIV(E_, 256), nbN = CDIV(N_, 256);
  const int MMB = CDIV(N_, 64);

  hipMemsetAsync(cnt, 0, (size_t)N_ * 4, stream);
  k_count<<<nbE, 256, 0, stream>>>(dst, cnt);
  k_dinv<<<nbN, 256, 0, stream>>>(cnt, dinv);
  k_scan1<<<nbN, 256, 0, stream>>>(cnt, ro, bs);
  k_scan2<<<1, 512, 0, stream>>>(bs, nbN);
  k_scan3<<<CDIV(N_ + 1, 256), 256, 0, stream>>>(ro, bs);
  hipMemsetAsync(cur, 0, (size_t)N_ * 4, stream);
  k_fill<<<nbE, 256, 0, stream>>>(src, dst, ro, cur, csr);
  k_bounds<<<CDIV(G_ + 1, 256), 256, 0, stream>>>(batch, gstart);
  k_wprep<<<8, 256, 0, stream>>>(W1, wt1);
  k_wprep<<<8, 256, 0, stream>>>(W2, wt2);
  k_wprep<<<8, 256, 0, stream>>>(W3, wt3);
  k_wprep<<<8, 256, 0, stream>>>(Wa, wta);

  // L1
  k_mm_mfma<<<MMB, 256, 0, stream>>>(x, wt1, bufH, nullptr, nullptr, nullptr,
                                     dinv, nullptr, nullptr, nullptr, nullptr);
  k_gcn_agg2<<<AGG_BLOCKS, 256, 0, stream>>>(bufH, ro, csr, dinv, b1, bufY, pbuf);
  k_bn_reduce<<<64, 256, 0, stream>>>(pbuf, g1, be1, ss);
  // L2
  k_mm_mfma<<<MMB, 256, 0, stream>>>(bufY, wt2, bufH, ss, x, xres,
                                     dinv, nullptr, nullptr, nullptr, nullptr);
  k_gcn_agg2<<<AGG_BLOCKS, 256, 0, stream>>>(bufH, ro, csr, dinv, b2, bufY, pbuf);
  k_bn_reduce<<<64, 256, 0, stream>>>(pbuf, g2, be2, ss);
  // L3
  k_mm_mfma<<<MMB, 256, 0, stream>>>(bufY, wt3, bufH, ss, xres, xres,
                                     dinv, nullptr, nullptr, nullptr, nullptr);
  k_gcn_agg2<<<AGG_BLOCKS, 256, 0, stream>>>(bufH, ro, csr, dinv, b3, bufY, pbuf);
  k_bn_reduce<<<64, 256, 0, stream>>>(pbuf, g3, be3, ss);
  // GAT (no prescale; al/ar epilogue)
  k_mm_mfma<<<MMB, 256, 0, stream>>>(bufY, wta, bufH, ss, xres, nullptr,
                                     nullptr, a_src, a_dst, al, ar);
  k_gat_agg2<<<AGG_BLOCKS, 256, 0, stream>>>(bufH, ro, csr, al, ar, ba, bufY, pbuf);
  k_bn_reduce<<<64, 256, 0, stream>>>(pbuf, ga, bea, ss);
  // pool
  k_pool2<<<G_, 256, 0, stream>>>(bufY, gstart, ss, pooled);
  // MLP
  k_gemm<<<dim3(NHID_/64, G_/64), 256, 0, stream>>>(pooled, Wl1, bl1, m1, G_, D_, NHID_, 1);
  k_gemm<<<dim3(NHID_/64, G_/64), 256, 0, stream>>>(m1, Wl2, bl2, m2, G_, NHID_, NHID_, 1);
  k_gemm<<<dim3(NHID_/64, G_/64), 256, 0, stream>>>(m2, Wl3, bl3, m1, G_, NHID_, NHID_, 1);
  k_gemm<<<dim3(NOUT_/64, G_/64), 256, 0, stream>>>(m1, Wl4, bl4, m4, G_, NHID_, NOUT_, 0);
  k_layernorm<<<G_, 256, 0, stream>>>(m4, gln, bln, out);
}